// Round 14
// baseline (383.940 us; speedup 1.0000x reference)
//
#include <hip/hip_runtime.h>

#define NN 100000
#define EE 1600000
#define DD 128
#define FFD 512
#define EPSV 1e-5f

#define SCB 98   // scan blocks: ceil(100000/1024)

typedef __attribute__((ext_vector_type(8))) short bf16x8;
typedef __attribute__((ext_vector_type(4))) float f32x4;
typedef unsigned long long ull;

__device__ __forceinline__ ushort f2b(float f) {          // fp32 -> bf16 RNE
    uint u = __float_as_uint(f);
    return (ushort)((u + 0x7FFF + ((u >> 16) & 1)) >> 16);
}
__device__ __forceinline__ float b2f(ushort u) {
    return __uint_as_float(((uint)u) << 16);
}

// ---------------- init: pk=0, stats=0 ----------------

__global__ __launch_bounds__(256) void k_init(ull* pk, float* s1, float* s2) {
    int i = blockIdx.x * 256 + threadIdx.x;
    if (i < NN) pk[i] = 0ULL;
    if (blockIdx.x == 0) { s1[threadIdx.x] = 0.f; s2[threadIdx.x] = 0.f; }
}

// ---------------- edge pass: packed 64-bit atomic; old>>32 = within-bucket rank ----------------

__global__ __launch_bounds__(256) void k_edge_deg(const int* __restrict__ ei,
                                                  const float* __restrict__ ew,
                                                  ull* __restrict__ pk,
                                                  int* __restrict__ rank) {
    int e = blockIdx.x * 256 + threadIdx.x;
    if (e < EE) {
        int dst = ei[EE + e];
        uint fx = (uint)(ew[e] * 16777216.0f + 0.5f);
        ull old = atomicAdd(&pk[dst], (1ULL << 32) | (ull)fx);
        rank[e] = (int)(old >> 32);
    }
}

// ---------------- scan part 1: block sums; unpack pk -> cnt, dinv ----------------

__global__ __launch_bounds__(256) void k_scan_part(const ull* __restrict__ pk,
                                                   int* __restrict__ cnt,
                                                   float* __restrict__ dinv,
                                                   int* __restrict__ bsum) {
    __shared__ int red[4];
    int b = blockIdx.x, t = threadIdx.x;
    int base = b * 1024 + t * 4;
    int s = 0;
#pragma unroll
    for (int j = 0; j < 4; ++j) {
        int i = base + j;
        if (i < NN) {
            ull v = pk[i];
            int c = (int)(v >> 32);
            cnt[i] = c;
            dinv[i] = rsqrtf(1.0f + (float)(uint)(v & 0xFFFFFFFFu) * (1.0f / 16777216.0f));
            s += c;
        }
    }
#pragma unroll
    for (int d = 1; d < 64; d <<= 1) s += __shfl_xor(s, d);
    if ((t & 63) == 0) red[t >> 6] = s;
    __syncthreads();
    if (t == 0) bsum[b] = red[0] + red[1] + red[2] + red[3];
}

__global__ __launch_bounds__(128) void k_scan_base(int* __restrict__ bsum,
                                                   int* __restrict__ bbase,
                                                   int* __restrict__ start) {
    if (threadIdx.x == 0) {
        int run = 0;
        for (int i = 0; i < SCB; ++i) { bbase[i] = run; run += bsum[i]; }
        start[NN] = run;   // == EE
    }
}

__global__ __launch_bounds__(256) void k_scan_fin(const int* __restrict__ cnt,
                                                  const int* __restrict__ bbase,
                                                  int* __restrict__ start) {
    __shared__ int ts[256];
    int b = blockIdx.x, t = threadIdx.x;
    int base = b * 1024 + t * 4;
    int v[4];
    int s = 0;
#pragma unroll
    for (int j = 0; j < 4; ++j) {
        int i = base + j;
        v[j] = (i < NN) ? cnt[i] : 0;
        s += v[j];
    }
    ts[t] = s;
    __syncthreads();
    for (int d = 1; d < 256; d <<= 1) {
        int add = (t >= d) ? ts[t - d] : 0;
        __syncthreads();
        ts[t] += add;
        __syncthreads();
    }
    int run = bbase[b] + ts[t] - s;   // exclusive offset for this thread
#pragma unroll
    for (int j = 0; j < 4; ++j) {
        int i = base + j;
        if (i < NN) {
            start[i] = run;
            run += v[j];
        }
    }
}

// ---------------- fill CSR records (src, norm), ATOMIC-FREE via rank ----------------

__global__ __launch_bounds__(256) void k_fill(const int* __restrict__ ei,
                                              const float* __restrict__ ew,
                                              const float* __restrict__ dinv,
                                              const int* __restrict__ start,
                                              const int* __restrict__ rank,
                                              uint2* __restrict__ csr) {
    int e = blockIdx.x * 256 + threadIdx.x;
    if (e < EE) {
        int src = ei[e];
        int dst = ei[EE + e];
        float nrm = dinv[src] * ew[e] * dinv[dst];
        int pos = start[dst] + rank[e];
        csr[pos] = make_uint2((uint)src, __float_as_uint(nrm));
    }
}

// ---------------- one-time weight transpose + bf16 convert ----------------

__global__ __launch_bounds__(256) void k_wcvt(const float* __restrict__ W,
                                              const float* __restrict__ W1,
                                              const float* __restrict__ W2,
                                              ushort* __restrict__ WTb,
                                              ushort* __restrict__ W1Tb,
                                              ushort* __restrict__ W2Tb) {
    int i = blockIdx.x * 256 + threadIdx.x;
    if (i < 16384) {
        int n = i >> 7, k = i & 127;
        WTb[i] = f2b(W[k * 128 + n]);
    } else if (i < 16384 + 65536) {
        int j = i - 16384;
        int f = j >> 7, k = j & 127;
        W1Tb[j] = f2b(W1[k * 512 + f]);
    } else {
        int j = i - 16384 - 65536;
        int jj = j >> 9, f = j & 511;
        W2Tb[j] = f2b(W2[f * 128 + jj]);
    }
}

// ---------------- x -> bf16 ----------------

__global__ __launch_bounds__(256) void k_xb(const float* __restrict__ x,
                                            ushort* __restrict__ xb) {
    long i = (long)blockIdx.x * 256 + threadIdx.x;   // float4 units, NN*32 total
    float4 v = ((const float4*)x)[i];
    ushort4 o;
    o.x = f2b(v.x); o.y = f2b(v.y); o.z = f2b(v.z); o.w = f2b(v.w);
    ((ushort4*)xb)[i] = o;
}

// ---------------- gather: agg[n] = dinv[n]^2*x~[n] + sum_e norm*x~[src]  (bf16 out) ----------------

__global__ __launch_bounds__(256) void k_gather(const ushort* __restrict__ xb,
                                                const float* __restrict__ dinv,
                                                const int* __restrict__ start,
                                                const uint2* __restrict__ csr,
                                                ushort* __restrict__ aggx) {
    int t = threadIdx.x;
    int wv = t >> 6, l = t & 63;
    const uint* xbu = (const uint*)xb;
    uint* aggu = (uint*)aggx;

    for (int k = 0; k < 8; ++k) {
        int node = blockIdx.x * 32 + wv * 8 + k;   // grid = NN/32 -> always < NN
        int e0 = start[node], e1 = start[node + 1];
        float a0 = 0.f, a1 = 0.f;
        int i = e0;
        for (; i + 8 <= e1; i += 8) {
            uint2 rr[8];
            uint hh[8];
#pragma unroll
            for (int u = 0; u < 8; ++u) rr[u] = csr[i + u];
#pragma unroll
            for (int u = 0; u < 8; ++u) hh[u] = xbu[rr[u].x * 64 + l];
#pragma unroll
            for (int u = 0; u < 8; ++u) {
                float n = __uint_as_float(rr[u].y);
                a0 = fmaf(n, b2f((ushort)(hh[u] & 0xFFFF)), a0);
                a1 = fmaf(n, b2f((ushort)(hh[u] >> 16)), a1);
            }
        }
        if (i + 4 <= e1) {
            uint2 rr[4];
            uint hh[4];
#pragma unroll
            for (int u = 0; u < 4; ++u) rr[u] = csr[i + u];
#pragma unroll
            for (int u = 0; u < 4; ++u) hh[u] = xbu[rr[u].x * 64 + l];
#pragma unroll
            for (int u = 0; u < 4; ++u) {
                float n = __uint_as_float(rr[u].y);
                a0 = fmaf(n, b2f((ushort)(hh[u] & 0xFFFF)), a0);
                a1 = fmaf(n, b2f((ushort)(hh[u] >> 16)), a1);
            }
            i += 4;
        }
        for (; i < e1; ++i) {
            uint2 r0 = csr[i];
            uint h0 = xbu[r0.x * 64 + l];
            float n0 = __uint_as_float(r0.y);
            a0 = fmaf(n0, b2f((ushort)(h0 & 0xFFFF)), a0);
            a1 = fmaf(n0, b2f((ushort)(h0 >> 16)), a1);
        }
        float dv = dinv[node];
        float sl = dv * dv;
        uint hs = xbu[node * 64 + l];
        a0 = fmaf(sl, b2f((ushort)(hs & 0xFFFF)), a0);
        a1 = fmaf(sl, b2f((ushort)(hs >> 16)), a1);
        aggu[node * 64 + l] = (uint)f2b(a0) | ((uint)f2b(a1) << 16);
    }
}

// ---------------- conv GEMM: xyb = bf16(x~ + agg @ W + b) in-place over xb, BN1 stats fused ----------------

__global__ __launch_bounds__(256) void k_conv(const ushort* __restrict__ aggx,
                                              const ushort* __restrict__ WTb,
                                              const float* __restrict__ b,
                                              ushort* xyb,          // read residual, write y (same buffer)
                                              float* __restrict__ stats1) {
    __shared__ __align__(16) ushort xt[64][136];
    __shared__ __align__(16) ushort wt[128][136];
    int t = threadIdx.x;
    int row0 = blockIdx.x * 64;

    for (int i = t; i < 2048; i += 256) {
        int r = i >> 4, c8 = (i & 15) << 3;
        *(uint4*)&wt[r][c8] = ((const uint4*)WTb)[i];
    }
    for (int i = t; i < 1024; i += 256) {
        int r = i >> 4, c8 = (i & 15) << 3;
        int gr = row0 + r;
        uint4 v = make_uint4(0u, 0u, 0u, 0u);
        if (gr < NN) v = ((const uint4*)aggx)[(long)gr * 16 + (i & 15)];
        *(uint4*)&xt[r][c8] = v;
    }
    __syncthreads();

    int wv = t >> 6, l = t & 63;
    int lr = l & 15, lg = l >> 4;
    int rw = wv & 1, jw = wv >> 1;

    f32x4 z4 = {0.f, 0.f, 0.f, 0.f};
    f32x4 acc[4][2];
#pragma unroll
    for (int jt = 0; jt < 4; ++jt)
#pragma unroll
        for (int rt = 0; rt < 2; ++rt) acc[jt][rt] = z4;

#pragma unroll
    for (int ks = 0; ks < 4; ++ks) {
        bf16x8 qR0 = *(const bf16x8*)&xt[rw * 32 + lr][ks * 32 + lg * 8];
        bf16x8 qR1 = *(const bf16x8*)&xt[rw * 32 + 16 + lr][ks * 32 + lg * 8];
#pragma unroll
        for (int jt = 0; jt < 4; ++jt) {
            bf16x8 pW = *(const bf16x8*)&wt[jw * 64 + jt * 16 + lr][ks * 32 + lg * 8];
            acc[jt][0] = __builtin_amdgcn_mfma_f32_16x16x32_bf16(pW, qR0, acc[jt][0], 0, 0, 0);
            acc[jt][1] = __builtin_amdgcn_mfma_f32_16x16x32_bf16(pW, qR1, acc[jt][1], 0, 0, 0);
        }
    }

    // epilogue: z = x~ + acc + b -> xyb (bf16), BN1 partials
    float sj[4][4], qj[4][4];
#pragma unroll
    for (int jt = 0; jt < 4; ++jt)
#pragma unroll
        for (int g = 0; g < 4; ++g) { sj[jt][g] = 0.f; qj[jt][g] = 0.f; }

#pragma unroll
    for (int jt = 0; jt < 4; ++jt) {
        int jb = jw * 64 + jt * 16 + lg * 4;
        float4 bv = *(const float4*)&b[jb];
#pragma unroll
        for (int rt = 0; rt < 2; ++rt) {
            int rloc = rw * 32 + rt * 16 + lr;
            int r = row0 + rloc;
            if (r < NN) {
                ushort4 xv = *(const ushort4*)&xyb[(long)r * 128 + jb];
                float z0 = b2f(xv.x) + acc[jt][rt][0] + bv.x;
                float z1 = b2f(xv.y) + acc[jt][rt][1] + bv.y;
                float z2 = b2f(xv.z) + acc[jt][rt][2] + bv.z;
                float z3 = b2f(xv.w) + acc[jt][rt][3] + bv.w;
                ushort4 o;
                o.x = f2b(z0); o.y = f2b(z1); o.z = f2b(z2); o.w = f2b(z3);
                *(ushort4*)&xyb[(long)r * 128 + jb] = o;
                sj[jt][0] += z0; sj[jt][1] += z1; sj[jt][2] += z2; sj[jt][3] += z3;
                qj[jt][0] += z0 * z0; qj[jt][1] += z1 * z1; qj[jt][2] += z2 * z2; qj[jt][3] += z3 * z3;
            }
        }
    }
#pragma unroll
    for (int jt = 0; jt < 4; ++jt)
#pragma unroll
        for (int g = 0; g < 4; ++g) {
#pragma unroll
            for (int d = 1; d < 16; d <<= 1) {
                sj[jt][g] += __shfl_xor(sj[jt][g], d);
                qj[jt][g] += __shfl_xor(qj[jt][g], d);
            }
        }
    __syncthreads();   // xt reads done; reuse as reduction buffer
    float* redS = (float*)&xt[0][0];    // [4][128]
    float* redQ = redS + 512;           // [4][128]
    if (lr == 0) {
#pragma unroll
        for (int jt = 0; jt < 4; ++jt)
#pragma unroll
            for (int g = 0; g < 4; ++g) {
                int j = jw * 64 + jt * 16 + lg * 4 + g;
                redS[wv * 128 + j] = sj[jt][g];
                redQ[wv * 128 + j] = qj[jt][g];
            }
    }
    __syncthreads();
    if (t < 128) {
        int w0 = (t >> 6) * 2;
        atomicAdd(&stats1[t], redS[w0 * 128 + t] + redS[(w0 + 1) * 128 + t]);
        atomicAdd(&stats1[128 + t], redQ[w0 * 128 + t] + redQ[(w0 + 1) * 128 + t]);
    }
}

// ---------------- BN finalize + affine ----------------

__global__ __launch_bounds__(128) void k_bn_fin(const float* __restrict__ stats,
                                                const float* __restrict__ gamma,
                                                const float* __restrict__ beta,
                                                float* __restrict__ ac) {
    int c = threadIdx.x;
    float mu = stats[c] * (1.0f / NN);
    float var = stats[128 + c] * (1.0f / NN) - mu * mu;
    float a = gamma[c] * rsqrtf(var + EPSV);
    ac[c] = a;
    ac[128 + c] = beta[c] - mu * a;
}

__global__ __launch_bounds__(256) void k_affine(float* __restrict__ v,
                                                const float* __restrict__ ac) {
    long i = (long)blockIdx.x * 256 + threadIdx.x;   // float4 units
    int c4i = (int)(i & 31);
    float4 a = ((const float4*)ac)[c4i];
    float4 cc = ((const float4*)(ac + 128))[c4i];
    float4 v4 = ((float4*)v)[i];
    v4.x = a.x * v4.x + cc.x;
    v4.y = a.y * v4.y + cc.y;
    v4.z = a.z * v4.z + cc.z;
    v4.w = a.w * v4.w + cc.w;
    ((float4*)v)[i] = v4;
}

// ---------------- fused MLP v8: 128 rows, 16 waves (1024 thr), 96KB LDS, swizzled ----------------
// Swizzle: 16B block kb of row stored at kb ^ (row & 15). Row stride 128 ushorts (no pad).
// Waves: rw = wv&7 (16-row slice), jw = wv>>3 (64-col half). Wave tile 16r x 64f.

#define SWZ16(row, kb) ((((kb) ^ ((row) & 15)) << 3))

__global__ __launch_bounds__(1024) void k_mlp(const ushort* __restrict__ yb,
                                              const float* __restrict__ ac1,
                                              const ushort* __restrict__ W1Tb,
                                              const float* __restrict__ b1,
                                              const ushort* __restrict__ W2Tb,
                                              const float* __restrict__ b2,
                                              float* __restrict__ out,
                                              float* __restrict__ stats2) {
    __shared__ __align__(16) ushort xt[128 * 128];   // 32 KB
    __shared__ __align__(16) ushort ht[128 * 128];   // 32 KB
    __shared__ __align__(16) ushort wc[128 * 128];   // 32 KB
    int t = threadIdx.x;
    int row0 = blockIdx.x * 128;   // grid 782; last block partially out of range

    // stage x1 = affine(yb) -> bf16, swizzled (2048 x 16B)
    for (int i = t; i < 2048; i += 1024) {
        int r = i >> 4, kb = i & 15;
        int gr = row0 + r;
        ushort4 y0 = make_ushort4(0, 0, 0, 0), y1 = make_ushort4(0, 0, 0, 0);
        if (gr < NN) {
            long base = (long)gr * 32 + kb * 2;
            y0 = ((const ushort4*)yb)[base];
            y1 = ((const ushort4*)yb)[base + 1];
        }
        float4 a0 = ((const float4*)ac1)[kb * 2];
        float4 a1 = ((const float4*)ac1)[kb * 2 + 1];
        float4 c0 = ((const float4*)(ac1 + 128))[kb * 2];
        float4 c1 = ((const float4*)(ac1 + 128))[kb * 2 + 1];
        ushort4 o0, o1;
        o0.x = f2b(a0.x * b2f(y0.x) + c0.x);
        o0.y = f2b(a0.y * b2f(y0.y) + c0.y);
        o0.z = f2b(a0.z * b2f(y0.z) + c0.z);
        o0.w = f2b(a0.w * b2f(y0.w) + c0.w);
        o1.x = f2b(a1.x * b2f(y1.x) + c1.x);
        o1.y = f2b(a1.y * b2f(y1.y) + c1.y);
        o1.z = f2b(a1.z * b2f(y1.z) + c1.z);
        o1.w = f2b(a1.w * b2f(y1.w) + c1.w);
        ushort* dst = &xt[r * 128 + SWZ16(r, kb)];
        *(ushort4*)dst = o0;
        *(ushort4*)(dst + 4) = o1;
    }

    int wv = t >> 6, l = t & 63;
    int lr = l & 15, lg = l >> 4;
    int rw = wv & 7, jw = wv >> 3;
    int xrow = rw * 16 + lr;        // xrow & 15 == lr

    f32x4 z4 = {0.f, 0.f, 0.f, 0.f};
    f32x4 acc[4];
#pragma unroll
    for (int jt = 0; jt < 4; ++jt) acc[jt] = z4;

    for (int ch = 0; ch < 4; ++ch) {
        __syncthreads();   // wc free (prev GEMM2 done); xt staged (ch=0)
        // stage W1 chunk (128 f x 128 k), swizzled
        for (int i = t; i < 2048; i += 1024) {
            int f = i >> 4, kb = i & 15;
            uint4 v = ((const uint4*)W1Tb)[(ch * 128 + f) * 16 + kb];
            *(uint4*)&wc[f * 128 + SWZ16(f, kb)] = v;
        }
        __syncthreads();

        // GEMM1: hidden(16r x 64f per wave) = relu(x1 @ W1c + b1c)
        f32x4 hacc[4];
#pragma unroll
        for (int ft = 0; ft < 4; ++ft) hacc[ft] = z4;
#pragma unroll
        for (int ks = 0; ks < 4; ++ks) {
            int kcol = ((ks * 4 + lg) ^ lr) << 3;
            bf16x8 aR = *(const bf16x8*)&xt[xrow * 128 + kcol];
#pragma unroll
            for (int ft = 0; ft < 4; ++ft) {
                int f = jw * 64 + ft * 16 + lr;
                bf16x8 bW = *(const bf16x8*)&wc[f * 128 + kcol];
                hacc[ft] = __builtin_amdgcn_mfma_f32_16x16x32_bf16(aR, bW, hacc[ft], 0, 0, 0);
            }
        }
#pragma unroll
        for (int ft = 0; ft < 4; ++ft) {
            int fcol = jw * 64 + ft * 16 + lr;
            float b1v = b1[ch * 128 + fcol];
            int kbf = fcol >> 3, wi = fcol & 7;
#pragma unroll
            for (int rg = 0; rg < 4; ++rg) {
                int hrow = rw * 16 + lg * 4 + rg;
                ht[hrow * 128 + ((kbf ^ (hrow & 15)) << 3) + wi] =
                    f2b(fmaxf(hacc[ft][rg] + b1v, 0.f));
            }
        }
        __syncthreads();   // ht complete, wc free

        // stage W2 chunk (128 j x 128 f), swizzled
        for (int i = t; i < 2048; i += 1024) {
            int j = i >> 4, kb = i & 15;
            uint4 v = ((const uint4*)W2Tb)[j * 64 + ch * 16 + kb];
            *(uint4*)&wc[j * 128 + SWZ16(j, kb)] = v;
        }
        __syncthreads();

        // GEMM2 swapped: acc(j x r) += W2c-rows x ht-rows
#pragma unroll
        for (int ks = 0; ks < 4; ++ks) {
            int kcol = ((ks * 4 + lg) ^ lr) << 3;
            bf16x8 qR = *(const bf16x8*)&ht[xrow * 128 + kcol];
#pragma unroll
            for (int jt = 0; jt < 4; ++jt) {
                int j = jw * 64 + jt * 16 + lr;
                bf16x8 pW = *(const bf16x8*)&wc[j * 128 + kcol];
                acc[jt] = __builtin_amdgcn_mfma_f32_16x16x32_bf16(pW, qR, acc[jt], 0, 0, 0);
            }
        }
    }

    // epilogue: z = x1 + x2 + b2 (float4 stores), BN2 partials
    float sj[4][4], qj[4][4];
    int r = row0 + xrow;
#pragma unroll
    for (int jt = 0; jt < 4; ++jt) {
        int jb = jw * 64 + jt * 16 + lg * 4;
        float4 b2v = *(const float4*)&b2[jb];
        int kbj = jb >> 3, wj = jb & 7;
        ushort4 xv = *(const ushort4*)&xt[xrow * 128 + ((kbj ^ lr) << 3) + wj];
        float z0 = b2f(xv.x) + acc[jt][0] + b2v.x;
        float z1 = b2f(xv.y) + acc[jt][1] + b2v.y;
        float z2 = b2f(xv.z) + acc[jt][2] + b2v.z;
        float z3 = b2f(xv.w) + acc[jt][3] + b2v.w;
        if (r < NN) {
            *(float4*)&out[(long)r * 128 + jb] = make_float4(z0, z1, z2, z3);
            sj[jt][0] = z0; sj[jt][1] = z1; sj[jt][2] = z2; sj[jt][3] = z3;
            qj[jt][0] = z0 * z0; qj[jt][1] = z1 * z1; qj[jt][2] = z2 * z2; qj[jt][3] = z3 * z3;
        } else {
            sj[jt][0] = 0.f; sj[jt][1] = 0.f; sj[jt][2] = 0.f; sj[jt][3] = 0.f;
            qj[jt][0] = 0.f; qj[jt][1] = 0.f; qj[jt][2] = 0.f; qj[jt][3] = 0.f;
        }
    }
#pragma unroll
    for (int jt = 0; jt < 4; ++jt)
#pragma unroll
        for (int g = 0; g < 4; ++g) {
#pragma unroll
            for (int d = 1; d < 16; d <<= 1) {
                sj[jt][g] += __shfl_xor(sj[jt][g], d);
                qj[jt][g] += __shfl_xor(qj[jt][g], d);
            }
        }
    __syncthreads();   // ht reads done; reuse as reduction buffer
    float* redS = (float*)&ht[0];    // [16][128]
    float* redQ = redS + 2048;       // [16][128]
    if (lr == 0) {
#pragma unroll
        for (int jt = 0; jt < 4; ++jt)
#pragma unroll
            for (int g = 0; g < 4; ++g) {
                int j = jw * 64 + jt * 16 + lg * 4 + g;
                redS[wv * 128 + j] = sj[jt][g];
                redQ[wv * 128 + j] = qj[jt][g];
            }
    }
    __syncthreads();
    if (t < 128) {
        int h = t >> 6;   // j-half; owned by waves h*8 .. h*8+7
        float S = 0.f, Q = 0.f;
#pragma unroll
        for (int w = 0; w < 8; ++w) {
            S += redS[(h * 8 + w) * 128 + t];
            Q += redQ[(h * 8 + w) * 128 + t];
        }
        atomicAdd(&stats2[t], S);
        atomicAdd(&stats2[128 + t], Q);
    }
}

// ---------------- launch ----------------

extern "C" void kernel_launch(void* const* d_in, const int* in_sizes, int n_in,
                              void* d_out, int out_size, void* d_ws, size_t ws_size,
                              hipStream_t stream) {
    const float* x     = (const float*)d_in[0];
    const int*   ei    = (const int*)d_in[1];
    const float* ew    = (const float*)d_in[2];
    const float* W     = (const float*)d_in[3];
    const float* b     = (const float*)d_in[4];
    const float* gamma = (const float*)d_in[5];
    const float* beta  = (const float*)d_in[6];
    const float* W1    = (const float*)d_in[7];
    const float* b1    = (const float*)d_in[8];
    const float* W2    = (const float*)d_in[9];
    const float* b2    = (const float*)d_in[10];
    float* out = (float*)d_out;
    float* ws  = (float*)d_ws;

    ull*   pk     = (ull*)ws;                        // NN (8B each)
    float* dinv   = ws + 2 * NN;                     // NN
    float* stats1 = ws + 3 * NN;                     // 256
    float* ac1    = stats1 + 256;                    // 256
    float* stats2 = ac1 + 256;                       // 256
    float* ac2    = stats2 + 256;                    // 256
    ushort* xb    = (ushort*)(ws + 3 * NN + 1024);   // NN*128 bf16
    ushort* WTb   = xb + (long)NN * 128;             // 16384
    ushort* W1Tb  = WTb + 16384;                     // 65536
    ushort* W2Tb  = W1Tb + 65536;                    // 65536
    float*  fend  = ws + 3 * NN + 1024 + (long)NN * 64 + 73728;
    int*   cnt    = (int*)fend;                      // NN
    int*   start  = cnt + NN;                        // NN+1
    int*   bsum   = start + NN + 1;                  // SCB
    int*   bbase  = bsum + SCB;                      // SCB
    uint2* csr    = (uint2*)(((uintptr_t)(bbase + SCB) + 7) & ~(uintptr_t)7);  // EE records
    ushort* aggx  = (ushort*)(csr + EE);             // NN*128 bf16
    int*   rank   = (int*)aggx;                      // EE ints; lifetime before aggx (disjoint)
    ushort* yb    = xb;                              // xb becomes y (bf16) in-place in k_conv

    int nb = (NN + 63) / 64;     // 1563
    int nm = (NN + 127) / 128;   // 782

    k_init<<<(NN + 255) / 256, 256, 0, stream>>>(pk, stats1, stats2);
    k_edge_deg<<<EE / 256, 256, 0, stream>>>(ei, ew, pk, rank);
    k_scan_part<<<SCB, 256, 0, stream>>>(pk, cnt, dinv, bsum);
    k_scan_base<<<1, 128, 0, stream>>>(bsum, bbase, start);
    k_scan_fin<<<SCB, 256, 0, stream>>>(cnt, bbase, start);
    k_fill<<<EE / 256, 256, 0, stream>>>(ei, ew, dinv, start, rank, csr);
    k_wcvt<<<576, 256, 0, stream>>>(W, W1, W2, WTb, W1Tb, W2Tb);
    k_xb<<<(NN * 32) / 256, 256, 0, stream>>>(x, xb);
    k_gather<<<NN / 32, 256, 0, stream>>>(xb, dinv, start, csr, aggx);
    k_conv<<<nb, 256, 0, stream>>>(aggx, WTb, b, yb, stats1);
    k_bn_fin<<<1, 128, 0, stream>>>(stats1, gamma, beta, ac1);
    k_mlp<<<nm, 1024, 0, stream>>>(yb, ac1, W1Tb, b1, W2Tb, b2, out, stats2);
    k_bn_fin<<<1, 128, 0, stream>>>(stats2, gamma, beta, ac2);
    k_affine<<<(NN * 32) / 256, 256, 0, stream>>>(out, ac2);
}

// Round 15
// 360.557 us; speedup vs baseline: 1.0649x; 1.0649x over previous
//
#include <hip/hip_runtime.h>

#define NN 100000
#define EE 1600000
#define DD 128
#define FFD 512
#define EPSV 1e-5f

#define SCB 98      // scan blocks: ceil(100000/1024)
#define EB 6250     // edge blocks in k_pre
#define MIXB 18750  // EB*3 (1 edge : 2 xb interleave)

typedef __attribute__((ext_vector_type(8))) short bf16x8;
typedef __attribute__((ext_vector_type(4))) float f32x4;
typedef unsigned long long ull;

__device__ __forceinline__ ushort f2b(float f) {          // fp32 -> bf16 RNE
    uint u = __float_as_uint(f);
    return (ushort)((u + 0x7FFF + ((u >> 16) & 1)) >> 16);
}
__device__ __forceinline__ float b2f(ushort u) {
    return __uint_as_float(((uint)u) << 16);
}

// ---------------- init: pk=0, stats=0 ----------------

__global__ __launch_bounds__(256) void k_init(ull* pk, float* s1, float* s2) {
    int i = blockIdx.x * 256 + threadIdx.x;
    if (i < NN) pk[i] = 0ULL;
    if (blockIdx.x == 0) { s1[threadIdx.x] = 0.f; s2[threadIdx.x] = 0.f; }
}

// ---------------- fused pre-pass: edge_deg (atomics) || x->bf16 || weight cvt ----------------
// Interleaved 1 edge-block : 2 xb-blocks so streaming work hides under atomic latency.

__global__ __launch_bounds__(256) void k_pre(const int* __restrict__ ei,
                                             const float* __restrict__ ew,
                                             ull* __restrict__ pk,
                                             int* __restrict__ rank,
                                             const float* __restrict__ x,
                                             ushort* __restrict__ xb,
                                             const float* __restrict__ W,
                                             const float* __restrict__ W1,
                                             const float* __restrict__ W2,
                                             ushort* __restrict__ WTb,
                                             ushort* __restrict__ W1Tb,
                                             ushort* __restrict__ W2Tb) {
    int bid = blockIdx.x;
    int t = threadIdx.x;
    if (bid < MIXB) {
        if (bid % 3 == 0) {
            // edge_deg: packed 64-bit atomic; old>>32 = within-bucket rank
            int e = (bid / 3) * 256 + t;   // EB*256 == EE exactly
            int dst = ei[EE + e];
            uint fx = (uint)(ew[e] * 16777216.0f + 0.5f);
            ull old = atomicAdd(&pk[dst], (1ULL << 32) | (ull)fx);
            rank[e] = (int)(old >> 32);
        } else {
            // x -> bf16 (float4 granularity)
            int xbk = bid - bid / 3 - 1;   // 0..12499
            long i = (long)xbk * 256 + t;
            float4 v = ((const float4*)x)[i];
            ushort4 o;
            o.x = f2b(v.x); o.y = f2b(v.y); o.z = f2b(v.z); o.w = f2b(v.w);
            ((ushort4*)xb)[i] = o;
        }
    } else {
        // weight transpose + bf16 convert (576 blocks * 256 = 147456 elements)
        int i = (bid - MIXB) * 256 + t;
        if (i < 16384) {
            int n = i >> 7, k = i & 127;
            WTb[i] = f2b(W[k * 128 + n]);
        } else if (i < 16384 + 65536) {
            int j = i - 16384;
            int f = j >> 7, k = j & 127;
            W1Tb[j] = f2b(W1[k * 512 + f]);
        } else {
            int j = i - 16384 - 65536;
            int jj = j >> 9, f = j & 511;
            W2Tb[j] = f2b(W2[f * 128 + jj]);
        }
    }
}

// ---------------- scan part 1: block sums; unpack pk -> cnt, dinv ----------------

__global__ __launch_bounds__(256) void k_scan_part(const ull* __restrict__ pk,
                                                   int* __restrict__ cnt,
                                                   float* __restrict__ dinv,
                                                   int* __restrict__ bsum) {
    __shared__ int red[4];
    int b = blockIdx.x, t = threadIdx.x;
    int base = b * 1024 + t * 4;
    int s = 0;
#pragma unroll
    for (int j = 0; j < 4; ++j) {
        int i = base + j;
        if (i < NN) {
            ull v = pk[i];
            int c = (int)(v >> 32);
            cnt[i] = c;
            dinv[i] = rsqrtf(1.0f + (float)(uint)(v & 0xFFFFFFFFu) * (1.0f / 16777216.0f));
            s += c;
        }
    }
#pragma unroll
    for (int d = 1; d < 64; d <<= 1) s += __shfl_xor(s, d);
    if ((t & 63) == 0) red[t >> 6] = s;
    __syncthreads();
    if (t == 0) bsum[b] = red[0] + red[1] + red[2] + red[3];
}

__global__ __launch_bounds__(128) void k_scan_base(int* __restrict__ bsum,
                                                   int* __restrict__ bbase,
                                                   int* __restrict__ start) {
    if (threadIdx.x == 0) {
        int run = 0;
        for (int i = 0; i < SCB; ++i) { bbase[i] = run; run += bsum[i]; }
        start[NN] = run;   // == EE
    }
}

__global__ __launch_bounds__(256) void k_scan_fin(const int* __restrict__ cnt,
                                                  const int* __restrict__ bbase,
                                                  int* __restrict__ start) {
    __shared__ int ts[256];
    int b = blockIdx.x, t = threadIdx.x;
    int base = b * 1024 + t * 4;
    int v[4];
    int s = 0;
#pragma unroll
    for (int j = 0; j < 4; ++j) {
        int i = base + j;
        v[j] = (i < NN) ? cnt[i] : 0;
        s += v[j];
    }
    ts[t] = s;
    __syncthreads();
    for (int d = 1; d < 256; d <<= 1) {
        int add = (t >= d) ? ts[t - d] : 0;
        __syncthreads();
        ts[t] += add;
        __syncthreads();
    }
    int run = bbase[b] + ts[t] - s;   // exclusive offset for this thread
#pragma unroll
    for (int j = 0; j < 4; ++j) {
        int i = base + j;
        if (i < NN) {
            start[i] = run;
            run += v[j];
        }
    }
}

// ---------------- fill CSR records (src, norm), ATOMIC-FREE via rank ----------------

__global__ __launch_bounds__(256) void k_fill(const int* __restrict__ ei,
                                              const float* __restrict__ ew,
                                              const float* __restrict__ dinv,
                                              const int* __restrict__ start,
                                              const int* __restrict__ rank,
                                              uint2* __restrict__ csr) {
    int e = blockIdx.x * 256 + threadIdx.x;
    if (e < EE) {
        int src = ei[e];
        int dst = ei[EE + e];
        float nrm = dinv[src] * ew[e] * dinv[dst];
        int pos = start[dst] + rank[e];
        csr[pos] = make_uint2((uint)src, __float_as_uint(nrm));
    }
}

// ---------------- gather: agg[n] = dinv[n]^2*x~[n] + sum_e norm*x~[src]  (bf16 out) ----------------

__global__ __launch_bounds__(256) void k_gather(const ushort* __restrict__ xb,
                                                const float* __restrict__ dinv,
                                                const int* __restrict__ start,
                                                const uint2* __restrict__ csr,
                                                ushort* __restrict__ aggx) {
    int t = threadIdx.x;
    int wv = t >> 6, l = t & 63;
    const uint* xbu = (const uint*)xb;
    uint* aggu = (uint*)aggx;

    for (int k = 0; k < 8; ++k) {
        int node = blockIdx.x * 32 + wv * 8 + k;   // grid = NN/32 -> always < NN
        int e0 = start[node], e1 = start[node + 1];
        float a0 = 0.f, a1 = 0.f;
        int i = e0;
        for (; i + 8 <= e1; i += 8) {
            uint2 rr[8];
            uint hh[8];
#pragma unroll
            for (int u = 0; u < 8; ++u) rr[u] = csr[i + u];
#pragma unroll
            for (int u = 0; u < 8; ++u) hh[u] = xbu[rr[u].x * 64 + l];
#pragma unroll
            for (int u = 0; u < 8; ++u) {
                float n = __uint_as_float(rr[u].y);
                a0 = fmaf(n, b2f((ushort)(hh[u] & 0xFFFF)), a0);
                a1 = fmaf(n, b2f((ushort)(hh[u] >> 16)), a1);
            }
        }
        if (i + 4 <= e1) {
            uint2 rr[4];
            uint hh[4];
#pragma unroll
            for (int u = 0; u < 4; ++u) rr[u] = csr[i + u];
#pragma unroll
            for (int u = 0; u < 4; ++u) hh[u] = xbu[rr[u].x * 64 + l];
#pragma unroll
            for (int u = 0; u < 4; ++u) {
                float n = __uint_as_float(rr[u].y);
                a0 = fmaf(n, b2f((ushort)(hh[u] & 0xFFFF)), a0);
                a1 = fmaf(n, b2f((ushort)(hh[u] >> 16)), a1);
            }
            i += 4;
        }
        for (; i < e1; ++i) {
            uint2 r0 = csr[i];
            uint h0 = xbu[r0.x * 64 + l];
            float n0 = __uint_as_float(r0.y);
            a0 = fmaf(n0, b2f((ushort)(h0 & 0xFFFF)), a0);
            a1 = fmaf(n0, b2f((ushort)(h0 >> 16)), a1);
        }
        float dv = dinv[node];
        float sl = dv * dv;
        uint hs = xbu[node * 64 + l];
        a0 = fmaf(sl, b2f((ushort)(hs & 0xFFFF)), a0);
        a1 = fmaf(sl, b2f((ushort)(hs >> 16)), a1);
        aggu[node * 64 + l] = (uint)f2b(a0) | ((uint)f2b(a1) << 16);
    }
}

// ---------------- conv GEMM: xyb = bf16(x~ + agg @ W + b) in-place over xb, BN1 stats fused ----------------

__global__ __launch_bounds__(256) void k_conv(const ushort* __restrict__ aggx,
                                              const ushort* __restrict__ WTb,
                                              const float* __restrict__ b,
                                              ushort* xyb,          // read residual, write y (same buffer)
                                              float* __restrict__ stats1) {
    __shared__ __align__(16) ushort xt[64][136];
    __shared__ __align__(16) ushort wt[128][136];
    int t = threadIdx.x;
    int row0 = blockIdx.x * 64;

    for (int i = t; i < 2048; i += 256) {
        int r = i >> 4, c8 = (i & 15) << 3;
        *(uint4*)&wt[r][c8] = ((const uint4*)WTb)[i];
    }
    for (int i = t; i < 1024; i += 256) {
        int r = i >> 4, c8 = (i & 15) << 3;
        int gr = row0 + r;
        uint4 v = make_uint4(0u, 0u, 0u, 0u);
        if (gr < NN) v = ((const uint4*)aggx)[(long)gr * 16 + (i & 15)];
        *(uint4*)&xt[r][c8] = v;
    }
    __syncthreads();

    int wv = t >> 6, l = t & 63;
    int lr = l & 15, lg = l >> 4;
    int rw = wv & 1, jw = wv >> 1;

    f32x4 z4 = {0.f, 0.f, 0.f, 0.f};
    f32x4 acc[4][2];
#pragma unroll
    for (int jt = 0; jt < 4; ++jt)
#pragma unroll
        for (int rt = 0; rt < 2; ++rt) acc[jt][rt] = z4;

#pragma unroll
    for (int ks = 0; ks < 4; ++ks) {
        bf16x8 qR0 = *(const bf16x8*)&xt[rw * 32 + lr][ks * 32 + lg * 8];
        bf16x8 qR1 = *(const bf16x8*)&xt[rw * 32 + 16 + lr][ks * 32 + lg * 8];
#pragma unroll
        for (int jt = 0; jt < 4; ++jt) {
            bf16x8 pW = *(const bf16x8*)&wt[jw * 64 + jt * 16 + lr][ks * 32 + lg * 8];
            acc[jt][0] = __builtin_amdgcn_mfma_f32_16x16x32_bf16(pW, qR0, acc[jt][0], 0, 0, 0);
            acc[jt][1] = __builtin_amdgcn_mfma_f32_16x16x32_bf16(pW, qR1, acc[jt][1], 0, 0, 0);
        }
    }

    // epilogue: z = x~ + acc + b -> xyb (bf16), BN1 partials
    float sj[4][4], qj[4][4];
#pragma unroll
    for (int jt = 0; jt < 4; ++jt)
#pragma unroll
        for (int g = 0; g < 4; ++g) { sj[jt][g] = 0.f; qj[jt][g] = 0.f; }

#pragma unroll
    for (int jt = 0; jt < 4; ++jt) {
        int jb = jw * 64 + jt * 16 + lg * 4;
        float4 bv = *(const float4*)&b[jb];
#pragma unroll
        for (int rt = 0; rt < 2; ++rt) {
            int rloc = rw * 32 + rt * 16 + lr;
            int r = row0 + rloc;
            if (r < NN) {
                ushort4 xv = *(const ushort4*)&xyb[(long)r * 128 + jb];
                float z0 = b2f(xv.x) + acc[jt][rt][0] + bv.x;
                float z1 = b2f(xv.y) + acc[jt][rt][1] + bv.y;
                float z2 = b2f(xv.z) + acc[jt][rt][2] + bv.z;
                float z3 = b2f(xv.w) + acc[jt][rt][3] + bv.w;
                ushort4 o;
                o.x = f2b(z0); o.y = f2b(z1); o.z = f2b(z2); o.w = f2b(z3);
                *(ushort4*)&xyb[(long)r * 128 + jb] = o;
                sj[jt][0] += z0; sj[jt][1] += z1; sj[jt][2] += z2; sj[jt][3] += z3;
                qj[jt][0] += z0 * z0; qj[jt][1] += z1 * z1; qj[jt][2] += z2 * z2; qj[jt][3] += z3 * z3;
            }
        }
    }
#pragma unroll
    for (int jt = 0; jt < 4; ++jt)
#pragma unroll
        for (int g = 0; g < 4; ++g) {
#pragma unroll
            for (int d = 1; d < 16; d <<= 1) {
                sj[jt][g] += __shfl_xor(sj[jt][g], d);
                qj[jt][g] += __shfl_xor(qj[jt][g], d);
            }
        }
    __syncthreads();   // xt reads done; reuse as reduction buffer
    float* redS = (float*)&xt[0][0];    // [4][128]
    float* redQ = redS + 512;           // [4][128]
    if (lr == 0) {
#pragma unroll
        for (int jt = 0; jt < 4; ++jt)
#pragma unroll
            for (int g = 0; g < 4; ++g) {
                int j = jw * 64 + jt * 16 + lg * 4 + g;
                redS[wv * 128 + j] = sj[jt][g];
                redQ[wv * 128 + j] = qj[jt][g];
            }
    }
    __syncthreads();
    if (t < 128) {
        int w0 = (t >> 6) * 2;
        atomicAdd(&stats1[t], redS[w0 * 128 + t] + redS[(w0 + 1) * 128 + t]);
        atomicAdd(&stats1[128 + t], redQ[w0 * 128 + t] + redQ[(w0 + 1) * 128 + t]);
    }
}

// ---------------- BN finalize ----------------

__global__ __launch_bounds__(128) void k_bn_fin(const float* __restrict__ stats,
                                                const float* __restrict__ gamma,
                                                const float* __restrict__ beta,
                                                float* __restrict__ ac) {
    int c = threadIdx.x;
    float mu = stats[c] * (1.0f / NN);
    float var = stats[128 + c] * (1.0f / NN) - mu * mu;
    float a = gamma[c] * rsqrtf(var + EPSV);
    ac[c] = a;
    ac[128 + c] = beta[c] - mu * a;
}

// ---------------- final affine: out = a * zb + c (bf16 in, fp32 out) ----------------

__global__ __launch_bounds__(256) void k_affine2(const ushort* __restrict__ zb,
                                                 const float* __restrict__ ac,
                                                 float* __restrict__ out) {
    long i = (long)blockIdx.x * 256 + threadIdx.x;   // float4 units
    int c4i = (int)(i & 31);
    float4 a = ((const float4*)ac)[c4i];
    float4 cc = ((const float4*)(ac + 128))[c4i];
    ushort4 zv = ((const ushort4*)zb)[i];
    float4 o;
    o.x = a.x * b2f(zv.x) + cc.x;
    o.y = a.y * b2f(zv.y) + cc.y;
    o.z = a.z * b2f(zv.z) + cc.z;
    o.w = a.w * b2f(zv.w) + cc.w;
    ((float4*)out)[i] = o;
}

// ---------------- fused MLP v7 (proven 101us): 64 rows, 8 waves, swizzled 64KB LDS; bf16 out ----------------
// Swizzle: 16B block kb of row stored at kb ^ (row & 15). Row stride 128 ushorts (no pad).
// Waves: rw = wv&3 (16-row quarter), jw = wv>>2 (64-col half). Wave tile 16r x 64f.

#define SWZ16(row, kb) ((((kb) ^ ((row) & 15)) << 3))

__global__ __launch_bounds__(512, 4) void k_mlp(const ushort* __restrict__ yb,
                                                const float* __restrict__ ac1,
                                                const ushort* __restrict__ W1Tb,
                                                const float* __restrict__ b1,
                                                const ushort* __restrict__ W2Tb,
                                                const float* __restrict__ b2,
                                                ushort* __restrict__ zb,
                                                float* __restrict__ stats2) {
    __shared__ __align__(16) ushort xt[64 * 128];   // 16 KB
    __shared__ __align__(16) ushort ht[64 * 128];   // 16 KB
    __shared__ __align__(16) ushort wc[128 * 128];  // 32 KB
    int t = threadIdx.x;
    int row0 = blockIdx.x * 64;   // grid 1563; last block partially out of range

    // stage x1 = affine(yb) -> bf16, swizzled (1024 x 16B)
    for (int i = t; i < 1024; i += 512) {
        int r = i >> 4, kb = i & 15;
        int gr = row0 + r;
        ushort4 y0 = make_ushort4(0, 0, 0, 0), y1 = make_ushort4(0, 0, 0, 0);
        if (gr < NN) {
            long base = (long)gr * 32 + kb * 2;
            y0 = ((const ushort4*)yb)[base];
            y1 = ((const ushort4*)yb)[base + 1];
        }
        float4 a0 = ((const float4*)ac1)[kb * 2];
        float4 a1 = ((const float4*)ac1)[kb * 2 + 1];
        float4 c0 = ((const float4*)(ac1 + 128))[kb * 2];
        float4 c1 = ((const float4*)(ac1 + 128))[kb * 2 + 1];
        ushort4 o0, o1;
        o0.x = f2b(a0.x * b2f(y0.x) + c0.x);
        o0.y = f2b(a0.y * b2f(y0.y) + c0.y);
        o0.z = f2b(a0.z * b2f(y0.z) + c0.z);
        o0.w = f2b(a0.w * b2f(y0.w) + c0.w);
        o1.x = f2b(a1.x * b2f(y1.x) + c1.x);
        o1.y = f2b(a1.y * b2f(y1.y) + c1.y);
        o1.z = f2b(a1.z * b2f(y1.z) + c1.z);
        o1.w = f2b(a1.w * b2f(y1.w) + c1.w);
        ushort* dst = &xt[r * 128 + SWZ16(r, kb)];
        *(ushort4*)dst = o0;
        *(ushort4*)(dst + 4) = o1;
    }

    int wv = t >> 6, l = t & 63;
    int lr = l & 15, lg = l >> 4;
    int rw = wv & 3, jw = wv >> 2;
    int xrow = rw * 16 + lr;        // xrow & 15 == lr

    f32x4 z4 = {0.f, 0.f, 0.f, 0.f};
    f32x4 acc[4];
#pragma unroll
    for (int jt = 0; jt < 4; ++jt) acc[jt] = z4;

    for (int ch = 0; ch < 4; ++ch) {
        __syncthreads();   // wc free (prev GEMM2 done); xt staged (ch=0)
        // stage W1 chunk (128 f x 128 k), swizzled
        for (int i = t; i < 2048; i += 512) {
            int f = i >> 4, kb = i & 15;
            uint4 v = ((const uint4*)W1Tb)[(ch * 128 + f) * 16 + kb];
            *(uint4*)&wc[f * 128 + SWZ16(f, kb)] = v;
        }
        __syncthreads();

        // GEMM1: hidden(16r x 64f per wave) = relu(x1 @ W1c + b1c)
        f32x4 hacc[4];
#pragma unroll
        for (int ft = 0; ft < 4; ++ft) hacc[ft] = z4;
#pragma unroll
        for (int ks = 0; ks < 4; ++ks) {
            int kcol = ((ks * 4 + lg) ^ lr) << 3;
            bf16x8 aR = *(const bf16x8*)&xt[xrow * 128 + kcol];
#pragma unroll
            for (int ft = 0; ft < 4; ++ft) {
                int f = jw * 64 + ft * 16 + lr;
                bf16x8 bW = *(const bf16x8*)&wc[f * 128 + kcol];
                hacc[ft] = __builtin_amdgcn_mfma_f32_16x16x32_bf16(aR, bW, hacc[ft], 0, 0, 0);
            }
        }
#pragma unroll
        for (int ft = 0; ft < 4; ++ft) {
            int fcol = jw * 64 + ft * 16 + lr;
            float b1v = b1[ch * 128 + fcol];
            int kbf = fcol >> 3, wi = fcol & 7;
#pragma unroll
            for (int rg = 0; rg < 4; ++rg) {
                int hrow = rw * 16 + lg * 4 + rg;
                ht[hrow * 128 + ((kbf ^ (hrow & 15)) << 3) + wi] =
                    f2b(fmaxf(hacc[ft][rg] + b1v, 0.f));
            }
        }
        __syncthreads();   // ht complete, wc free

        // stage W2 chunk (128 j x 128 f), swizzled
        for (int i = t; i < 2048; i += 512) {
            int j = i >> 4, kb = i & 15;
            uint4 v = ((const uint4*)W2Tb)[j * 64 + ch * 16 + kb];
            *(uint4*)&wc[j * 128 + SWZ16(j, kb)] = v;
        }
        __syncthreads();

        // GEMM2 swapped: acc(j x r) += W2c-rows x ht-rows
#pragma unroll
        for (int ks = 0; ks < 4; ++ks) {
            int kcol = ((ks * 4 + lg) ^ lr) << 3;
            bf16x8 qR = *(const bf16x8*)&ht[xrow * 128 + kcol];
#pragma unroll
            for (int jt = 0; jt < 4; ++jt) {
                int j = jw * 64 + jt * 16 + lr;
                bf16x8 pW = *(const bf16x8*)&wc[j * 128 + kcol];
                acc[jt] = __builtin_amdgcn_mfma_f32_16x16x32_bf16(pW, qR, acc[jt], 0, 0, 0);
            }
        }
    }

    // epilogue: z = x1 + x2 + b2 -> zb (bf16), BN2 partials
    float sj[4][4], qj[4][4];
    int r = row0 + xrow;
#pragma unroll
    for (int jt = 0; jt < 4; ++jt) {
        int jb = jw * 64 + jt * 16 + lg * 4;
        float4 b2v = *(const float4*)&b2[jb];
        int kbj = jb >> 3, wj = jb & 7;
        ushort4 xv = *(const ushort4*)&xt[xrow * 128 + ((kbj ^ lr) << 3) + wj];
        float z0 = b2f(xv.x) + acc[jt][0] + b2v.x;
        float z1 = b2f(xv.y) + acc[jt][1] + b2v.y;
        float z2 = b2f(xv.z) + acc[jt][2] + b2v.z;
        float z3 = b2f(xv.w) + acc[jt][3] + b2v.w;
        if (r < NN) {
            ushort4 o;
            o.x = f2b(z0); o.y = f2b(z1); o.z = f2b(z2); o.w = f2b(z3);
            *(ushort4*)&zb[(long)r * 128 + jb] = o;
            sj[jt][0] = z0; sj[jt][1] = z1; sj[jt][2] = z2; sj[jt][3] = z3;
            qj[jt][0] = z0 * z0; qj[jt][1] = z1 * z1; qj[jt][2] = z2 * z2; qj[jt][3] = z3 * z3;
        } else {
            sj[jt][0] = 0.f; sj[jt][1] = 0.f; sj[jt][2] = 0.f; sj[jt][3] = 0.f;
            qj[jt][0] = 0.f; qj[jt][1] = 0.f; qj[jt][2] = 0.f; qj[jt][3] = 0.f;
        }
    }
#pragma unroll
    for (int jt = 0; jt < 4; ++jt)
#pragma unroll
        for (int g = 0; g < 4; ++g) {
#pragma unroll
            for (int d = 1; d < 16; d <<= 1) {
                sj[jt][g] += __shfl_xor(sj[jt][g], d);
                qj[jt][g] += __shfl_xor(qj[jt][g], d);
            }
        }
    __syncthreads();   // ht reads done; reuse as reduction buffer
    float* redS = (float*)&ht[0];    // [8][128]
    float* redQ = redS + 1024;       // [8][128]
    if (lr == 0) {
#pragma unroll
        for (int jt = 0; jt < 4; ++jt)
#pragma unroll
            for (int g = 0; g < 4; ++g) {
                int j = jw * 64 + jt * 16 + lg * 4 + g;
                redS[wv * 128 + j] = sj[jt][g];
                redQ[wv * 128 + j] = qj[jt][g];
            }
    }
    __syncthreads();
    if (t < 128) {
        int h = t >> 6;   // j-half; owned by waves h*4 .. h*4+3
        float S = redS[(h * 4 + 0) * 128 + t] + redS[(h * 4 + 1) * 128 + t]
                + redS[(h * 4 + 2) * 128 + t] + redS[(h * 4 + 3) * 128 + t];
        float Q = redQ[(h * 4 + 0) * 128 + t] + redQ[(h * 4 + 1) * 128 + t]
                + redQ[(h * 4 + 2) * 128 + t] + redQ[(h * 4 + 3) * 128 + t];
        atomicAdd(&stats2[t], S);
        atomicAdd(&stats2[128 + t], Q);
    }
}

// ---------------- launch ----------------

extern "C" void kernel_launch(void* const* d_in, const int* in_sizes, int n_in,
                              void* d_out, int out_size, void* d_ws, size_t ws_size,
                              hipStream_t stream) {
    const float* x     = (const float*)d_in[0];
    const int*   ei    = (const int*)d_in[1];
    const float* ew    = (const float*)d_in[2];
    const float* W     = (const float*)d_in[3];
    const float* b     = (const float*)d_in[4];
    const float* gamma = (const float*)d_in[5];
    const float* beta  = (const float*)d_in[6];
    const float* W1    = (const float*)d_in[7];
    const float* b1    = (const float*)d_in[8];
    const float* W2    = (const float*)d_in[9];
    const float* b2    = (const float*)d_in[10];
    float* out = (float*)d_out;
    float* ws  = (float*)d_ws;

    ull*   pk     = (ull*)ws;                        // NN (8B each)
    float* dinv   = ws + 2 * NN;                     // NN
    float* stats1 = ws + 3 * NN;                     // 256
    float* ac1    = stats1 + 256;                    // 256
    float* stats2 = ac1 + 256;                       // 256
    float* ac2    = stats2 + 256;                    // 256
    ushort* xb    = (ushort*)(ws + 3 * NN + 1024);   // NN*128 bf16
    ushort* WTb   = xb + (long)NN * 128;             // 16384
    ushort* W1Tb  = WTb + 16384;                     // 65536
    ushort* W2Tb  = W1Tb + 65536;                    // 65536
    float*  fend  = ws + 3 * NN + 1024 + (long)NN * 64 + 73728;
    int*   cnt    = (int*)fend;                      // NN
    int*   start  = cnt + NN;                        // NN+1
    int*   bsum   = start + NN + 1;                  // SCB
    int*   bbase  = bsum + SCB;                      // SCB
    uint2* csr    = (uint2*)(((uintptr_t)(bbase + SCB) + 7) & ~(uintptr_t)7);  // EE records
    ushort* aggx  = (ushort*)(csr + EE);             // NN*128 bf16
    int*   rank   = (int*)aggx;                      // EE ints; lifetime before aggx (disjoint)
    ushort* yb    = xb;                              // xb becomes y (bf16) in-place in k_conv
    ushort* zb    = aggx;                            // aggx dead after k_conv; reuse for bf16 z

    int nb = (NN + 63) / 64;   // 1563

    k_init<<<(NN + 255) / 256, 256, 0, stream>>>(pk, stats1, stats2);
    k_pre<<<MIXB + 576, 256, 0, stream>>>(ei, ew, pk, rank, x, xb, W, W1, W2, WTb, W1Tb, W2Tb);
    k_scan_part<<<SCB, 256, 0, stream>>>(pk, cnt, dinv, bsum);
    k_scan_base<<<1, 128, 0, stream>>>(bsum, bbase, start);
    k_scan_fin<<<SCB, 256, 0, stream>>>(cnt, bbase, start);
    k_fill<<<EE / 256, 256, 0, stream>>>(ei, ew, dinv, start, rank, csr);
    k_gather<<<NN / 32, 256, 0, stream>>>(xb, dinv, start, csr, aggx);
    k_conv<<<nb, 256, 0, stream>>>(aggx, WTb, b, yb, stats1);
    k_bn_fin<<<1, 128, 0, stream>>>(stats1, gamma, beta, ac1);
    k_mlp<<<nb, 512, 0, stream>>>(yb, ac1, W1Tb, b1, W2Tb, b2, zb, stats2);
    k_bn_fin<<<1, 128, 0, stream>>>(stats2, gamma, beta, ac2);
    k_affine2<<<(NN * 32) / 256, 256, 0, stream>>>(zb, ac2, out);
}

// Round 16
// 346.029 us; speedup vs baseline: 1.1096x; 1.0420x over previous
//
#include <hip/hip_runtime.h>

#define NN 100000
#define EE 1600000
#define DD 128
#define FFD 512
#define EPSV 1e-5f

#define SCB 98      // scan blocks: ceil(100000/1024)
#define EB 6250     // edge blocks in k_pre
#define MIXB 18750  // EB*3 (1 edge : 2 xb interleave)

typedef __attribute__((ext_vector_type(8))) short bf16x8;
typedef __attribute__((ext_vector_type(4))) float f32x4;
typedef unsigned long long ull;

__device__ __forceinline__ ushort f2b(float f) {          // fp32 -> bf16 RNE
    uint u = __float_as_uint(f);
    return (ushort)((u + 0x7FFF + ((u >> 16) & 1)) >> 16);
}
__device__ __forceinline__ float b2f(ushort u) {
    return __uint_as_float(((uint)u) << 16);
}

// async 16B global->LDS copy (linear dest; vmcnt-drained by __syncthreads)
__device__ __forceinline__ void gld_lds16(const ushort* g, ushort* l) {
    __builtin_amdgcn_global_load_lds(
        (const __attribute__((address_space(1))) uint*)g,
        (__attribute__((address_space(3))) uint*)l, 16, 0, 0);
}

// ---------------- init: pk=0, stats=0 ----------------

__global__ __launch_bounds__(256) void k_init(ull* pk, float* s1, float* s2) {
    int i = blockIdx.x * 256 + threadIdx.x;
    if (i < NN) pk[i] = 0ULL;
    if (blockIdx.x == 0) { s1[threadIdx.x] = 0.f; s2[threadIdx.x] = 0.f; }
}

// ---------------- fused pre-pass: edge_deg (atomics) || x->bf16 || weight cvt ----------------
// W1img/W2img are stored as per-chunk 32KB LDS images (swizzle baked in) so k_mlp
// can stage them with linear global_load_lds.

__global__ __launch_bounds__(256) void k_pre(const int* __restrict__ ei,
                                             const float* __restrict__ ew,
                                             ull* __restrict__ pk,
                                             int* __restrict__ rank,
                                             const float* __restrict__ x,
                                             ushort* __restrict__ xb,
                                             const float* __restrict__ W,
                                             const float* __restrict__ W1,
                                             const float* __restrict__ W2,
                                             ushort* __restrict__ WTb,
                                             ushort* __restrict__ W1img,
                                             ushort* __restrict__ W2img) {
    int bid = blockIdx.x;
    int t = threadIdx.x;
    if (bid < MIXB) {
        if (bid % 3 == 0) {
            int e = (bid / 3) * 256 + t;   // EB*256 == EE exactly
            int dst = ei[EE + e];
            uint fx = (uint)(ew[e] * 16777216.0f + 0.5f);
            ull old = atomicAdd(&pk[dst], (1ULL << 32) | (ull)fx);
            rank[e] = (int)(old >> 32);
        } else {
            int xbk = bid - bid / 3 - 1;   // 0..12499
            long i = (long)xbk * 256 + t;
            float4 v = ((const float4*)x)[i];
            ushort4 o;
            o.x = f2b(v.x); o.y = f2b(v.y); o.z = f2b(v.z); o.w = f2b(v.w);
            ((ushort4*)xb)[i] = o;
        }
    } else {
        int i = (bid - MIXB) * 256 + t;
        if (i < 16384) {
            int n = i >> 7, k = i & 127;
            WTb[i] = f2b(W[k * 128 + n]);
        } else if (i < 16384 + 65536) {
            // W1img[u]: LDS image of chunk ch = swizzled [f_local][k] tile
            int u = i - 16384;
            int ch = u >> 14, rem = u & 16383;
            int f = rem >> 7, col = rem & 127;
            int kb = (col >> 3) ^ (f & 15);
            int j = col & 7;
            W1img[u] = f2b(W1[(kb * 8 + j) * 512 + ch * 128 + f]);
        } else {
            // W2img[u]: LDS image of chunk ch = swizzled [j_row][f_local] tile
            int u = i - 16384 - 65536;
            int ch = u >> 14, rem = u & 16383;
            int jrow = rem >> 7, col = rem & 127;
            int kb = (col >> 3) ^ (jrow & 15);
            int j2 = col & 7;
            W2img[u] = f2b(W2[(ch * 128 + kb * 8 + j2) * 128 + jrow]);
        }
    }
}

// ---------------- scan part 1: block sums; unpack pk -> cnt, dinv ----------------

__global__ __launch_bounds__(256) void k_scan_part(const ull* __restrict__ pk,
                                                   int* __restrict__ cnt,
                                                   float* __restrict__ dinv,
                                                   int* __restrict__ bsum) {
    __shared__ int red[4];
    int b = blockIdx.x, t = threadIdx.x;
    int base = b * 1024 + t * 4;
    int s = 0;
#pragma unroll
    for (int j = 0; j < 4; ++j) {
        int i = base + j;
        if (i < NN) {
            ull v = pk[i];
            int c = (int)(v >> 32);
            cnt[i] = c;
            dinv[i] = rsqrtf(1.0f + (float)(uint)(v & 0xFFFFFFFFu) * (1.0f / 16777216.0f));
            s += c;
        }
    }
#pragma unroll
    for (int d = 1; d < 64; d <<= 1) s += __shfl_xor(s, d);
    if ((t & 63) == 0) red[t >> 6] = s;
    __syncthreads();
    if (t == 0) bsum[b] = red[0] + red[1] + red[2] + red[3];
}

__global__ __launch_bounds__(128) void k_scan_base(int* __restrict__ bsum,
                                                   int* __restrict__ bbase,
                                                   int* __restrict__ start) {
    if (threadIdx.x == 0) {
        int run = 0;
        for (int i = 0; i < SCB; ++i) { bbase[i] = run; run += bsum[i]; }
        start[NN] = run;   // == EE
    }
}

__global__ __launch_bounds__(256) void k_scan_fin(const int* __restrict__ cnt,
                                                  const int* __restrict__ bbase,
                                                  int* __restrict__ start) {
    __shared__ int ts[256];
    int b = blockIdx.x, t = threadIdx.x;
    int base = b * 1024 + t * 4;
    int v[4];
    int s = 0;
#pragma unroll
    for (int j = 0; j < 4; ++j) {
        int i = base + j;
        v[j] = (i < NN) ? cnt[i] : 0;
        s += v[j];
    }
    ts[t] = s;
    __syncthreads();
    for (int d = 1; d < 256; d <<= 1) {
        int add = (t >= d) ? ts[t - d] : 0;
        __syncthreads();
        ts[t] += add;
        __syncthreads();
    }
    int run = bbase[b] + ts[t] - s;   // exclusive offset for this thread
#pragma unroll
    for (int j = 0; j < 4; ++j) {
        int i = base + j;
        if (i < NN) {
            start[i] = run;
            run += v[j];
        }
    }
}

// ---------------- fill CSR records (src, norm), ATOMIC-FREE via rank ----------------

__global__ __launch_bounds__(256) void k_fill(const int* __restrict__ ei,
                                              const float* __restrict__ ew,
                                              const float* __restrict__ dinv,
                                              const int* __restrict__ start,
                                              const int* __restrict__ rank,
                                              uint2* __restrict__ csr) {
    int e = blockIdx.x * 256 + threadIdx.x;
    if (e < EE) {
        int src = ei[e];
        int dst = ei[EE + e];
        float nrm = dinv[src] * ew[e] * dinv[dst];
        int pos = start[dst] + rank[e];
        csr[pos] = make_uint2((uint)src, __float_as_uint(nrm));
    }
}

// ---------------- gather: agg[n] = dinv[n]^2*x~[n] + sum_e norm*x~[src]  (bf16 out) ----------------

__global__ __launch_bounds__(256) void k_gather(const ushort* __restrict__ xb,
                                                const float* __restrict__ dinv,
                                                const int* __restrict__ start,
                                                const uint2* __restrict__ csr,
                                                ushort* __restrict__ aggx) {
    int t = threadIdx.x;
    int wv = t >> 6, l = t & 63;
    const uint* xbu = (const uint*)xb;
    uint* aggu = (uint*)aggx;

    for (int k = 0; k < 8; ++k) {
        int node = blockIdx.x * 32 + wv * 8 + k;   // grid = NN/32 -> always < NN
        int e0 = start[node], e1 = start[node + 1];
        float a0 = 0.f, a1 = 0.f;
        int i = e0;
        for (; i + 8 <= e1; i += 8) {
            uint2 rr[8];
            uint hh[8];
#pragma unroll
            for (int u = 0; u < 8; ++u) rr[u] = csr[i + u];
#pragma unroll
            for (int u = 0; u < 8; ++u) hh[u] = xbu[rr[u].x * 64 + l];
#pragma unroll
            for (int u = 0; u < 8; ++u) {
                float n = __uint_as_float(rr[u].y);
                a0 = fmaf(n, b2f((ushort)(hh[u] & 0xFFFF)), a0);
                a1 = fmaf(n, b2f((ushort)(hh[u] >> 16)), a1);
            }
        }
        if (i + 4 <= e1) {
            uint2 rr[4];
            uint hh[4];
#pragma unroll
            for (int u = 0; u < 4; ++u) rr[u] = csr[i + u];
#pragma unroll
            for (int u = 0; u < 4; ++u) hh[u] = xbu[rr[u].x * 64 + l];
#pragma unroll
            for (int u = 0; u < 4; ++u) {
                float n = __uint_as_float(rr[u].y);
                a0 = fmaf(n, b2f((ushort)(hh[u] & 0xFFFF)), a0);
                a1 = fmaf(n, b2f((ushort)(hh[u] >> 16)), a1);
            }
            i += 4;
        }
        for (; i < e1; ++i) {
            uint2 r0 = csr[i];
            uint h0 = xbu[r0.x * 64 + l];
            float n0 = __uint_as_float(r0.y);
            a0 = fmaf(n0, b2f((ushort)(h0 & 0xFFFF)), a0);
            a1 = fmaf(n0, b2f((ushort)(h0 >> 16)), a1);
        }
        float dv = dinv[node];
        float sl = dv * dv;
        uint hs = xbu[node * 64 + l];
        a0 = fmaf(sl, b2f((ushort)(hs & 0xFFFF)), a0);
        a1 = fmaf(sl, b2f((ushort)(hs >> 16)), a1);
        aggu[node * 64 + l] = (uint)f2b(a0) | ((uint)f2b(a1) << 16);
    }
}

// ---------------- conv GEMM: xyb = bf16(x~ + agg @ W + b) in-place over xb, BN1 stats fused ----------------

__global__ __launch_bounds__(256) void k_conv(const ushort* __restrict__ aggx,
                                              const ushort* __restrict__ WTb,
                                              const float* __restrict__ b,
                                              ushort* xyb,          // read residual, write y (same buffer)
                                              float* __restrict__ stats1) {
    __shared__ __align__(16) ushort xt[64][136];
    __shared__ __align__(16) ushort wt[128][136];
    int t = threadIdx.x;
    int row0 = blockIdx.x * 64;

    for (int i = t; i < 2048; i += 256) {
        int r = i >> 4, c8 = (i & 15) << 3;
        *(uint4*)&wt[r][c8] = ((const uint4*)WTb)[i];
    }
    for (int i = t; i < 1024; i += 256) {
        int r = i >> 4, c8 = (i & 15) << 3;
        int gr = row0 + r;
        uint4 v = make_uint4(0u, 0u, 0u, 0u);
        if (gr < NN) v = ((const uint4*)aggx)[(long)gr * 16 + (i & 15)];
        *(uint4*)&xt[r][c8] = v;
    }
    __syncthreads();

    int wv = t >> 6, l = t & 63;
    int lr = l & 15, lg = l >> 4;
    int rw = wv & 1, jw = wv >> 1;

    f32x4 z4 = {0.f, 0.f, 0.f, 0.f};
    f32x4 acc[4][2];
#pragma unroll
    for (int jt = 0; jt < 4; ++jt)
#pragma unroll
        for (int rt = 0; rt < 2; ++rt) acc[jt][rt] = z4;

#pragma unroll
    for (int ks = 0; ks < 4; ++ks) {
        bf16x8 qR0 = *(const bf16x8*)&xt[rw * 32 + lr][ks * 32 + lg * 8];
        bf16x8 qR1 = *(const bf16x8*)&xt[rw * 32 + 16 + lr][ks * 32 + lg * 8];
#pragma unroll
        for (int jt = 0; jt < 4; ++jt) {
            bf16x8 pW = *(const bf16x8*)&wt[jw * 64 + jt * 16 + lr][ks * 32 + lg * 8];
            acc[jt][0] = __builtin_amdgcn_mfma_f32_16x16x32_bf16(pW, qR0, acc[jt][0], 0, 0, 0);
            acc[jt][1] = __builtin_amdgcn_mfma_f32_16x16x32_bf16(pW, qR1, acc[jt][1], 0, 0, 0);
        }
    }

    // epilogue: z = x~ + acc + b -> xyb (bf16), BN1 partials
    float sj[4][4], qj[4][4];
#pragma unroll
    for (int jt = 0; jt < 4; ++jt)
#pragma unroll
        for (int g = 0; g < 4; ++g) { sj[jt][g] = 0.f; qj[jt][g] = 0.f; }

#pragma unroll
    for (int jt = 0; jt < 4; ++jt) {
        int jb = jw * 64 + jt * 16 + lg * 4;
        float4 bv = *(const float4*)&b[jb];
#pragma unroll
        for (int rt = 0; rt < 2; ++rt) {
            int rloc = rw * 32 + rt * 16 + lr;
            int r = row0 + rloc;
            if (r < NN) {
                ushort4 xv = *(const ushort4*)&xyb[(long)r * 128 + jb];
                float z0 = b2f(xv.x) + acc[jt][rt][0] + bv.x;
                float z1 = b2f(xv.y) + acc[jt][rt][1] + bv.y;
                float z2 = b2f(xv.z) + acc[jt][rt][2] + bv.z;
                float z3 = b2f(xv.w) + acc[jt][rt][3] + bv.w;
                ushort4 o;
                o.x = f2b(z0); o.y = f2b(z1); o.z = f2b(z2); o.w = f2b(z3);
                *(ushort4*)&xyb[(long)r * 128 + jb] = o;
                sj[jt][0] += z0; sj[jt][1] += z1; sj[jt][2] += z2; sj[jt][3] += z3;
                qj[jt][0] += z0 * z0; qj[jt][1] += z1 * z1; qj[jt][2] += z2 * z2; qj[jt][3] += z3 * z3;
            }
        }
    }
#pragma unroll
    for (int jt = 0; jt < 4; ++jt)
#pragma unroll
        for (int g = 0; g < 4; ++g) {
#pragma unroll
            for (int d = 1; d < 16; d <<= 1) {
                sj[jt][g] += __shfl_xor(sj[jt][g], d);
                qj[jt][g] += __shfl_xor(qj[jt][g], d);
            }
        }
    __syncthreads();   // xt reads done; reuse as reduction buffer
    float* redS = (float*)&xt[0][0];    // [4][128]
    float* redQ = redS + 512;           // [4][128]
    if (lr == 0) {
#pragma unroll
        for (int jt = 0; jt < 4; ++jt)
#pragma unroll
            for (int g = 0; g < 4; ++g) {
                int j = jw * 64 + jt * 16 + lg * 4 + g;
                redS[wv * 128 + j] = sj[jt][g];
                redQ[wv * 128 + j] = qj[jt][g];
            }
    }
    __syncthreads();
    if (t < 128) {
        int w0 = (t >> 6) * 2;
        atomicAdd(&stats1[t], redS[w0 * 128 + t] + redS[(w0 + 1) * 128 + t]);
        atomicAdd(&stats1[128 + t], redQ[w0 * 128 + t] + redQ[(w0 + 1) * 128 + t]);
    }
}

// ---------------- BN finalize ----------------

__global__ __launch_bounds__(128) void k_bn_fin(const float* __restrict__ stats,
                                                const float* __restrict__ gamma,
                                                const float* __restrict__ beta,
                                                float* __restrict__ ac) {
    int c = threadIdx.x;
    float mu = stats[c] * (1.0f / NN);
    float var = stats[128 + c] * (1.0f / NN) - mu * mu;
    float a = gamma[c] * rsqrtf(var + EPSV);
    ac[c] = a;
    ac[128 + c] = beta[c] - mu * a;
}

// ---------------- final affine: out = a * zb + c (bf16 in, fp32 out) ----------------

__global__ __launch_bounds__(256) void k_affine2(const ushort* __restrict__ zb,
                                                 const float* __restrict__ ac,
                                                 float* __restrict__ out) {
    long i = (long)blockIdx.x * 256 + threadIdx.x;   // float4 units
    int c4i = (int)(i & 31);
    float4 a = ((const float4*)ac)[c4i];
    float4 cc = ((const float4*)(ac + 128))[c4i];
    ushort4 zv = ((const ushort4*)zb)[i];
    float4 o;
    o.x = a.x * b2f(zv.x) + cc.x;
    o.y = a.y * b2f(zv.y) + cc.y;
    o.z = a.z * b2f(zv.z) + cc.z;
    o.w = a.w * b2f(zv.w) + cc.w;
    ((float4*)out)[i] = o;
}

// ---------------- fused MLP v9: v7 + async gload_lds weight staging from pre-swizzled images ----------------
// Swizzle: 16B block kb of row stored at kb ^ (row & 15). Row stride 128 ushorts (no pad).
// Waves: rw = wv&3 (16-row quarter), jw = wv>>2 (64-col half). Wave tile 16r x 64f.

#define SWZ16(row, kb) ((((kb) ^ ((row) & 15)) << 3))

__global__ __launch_bounds__(512, 4) void k_mlp(const ushort* __restrict__ yb,
                                                const float* __restrict__ ac1,
                                                const ushort* __restrict__ W1img,
                                                const float* __restrict__ b1,
                                                const ushort* __restrict__ W2img,
                                                const float* __restrict__ b2,
                                                ushort* __restrict__ zb,
                                                float* __restrict__ stats2) {
    __shared__ __align__(16) ushort xt[64 * 128];   // 16 KB
    __shared__ __align__(16) ushort ht[64 * 128];   // 16 KB
    __shared__ __align__(16) ushort wc[128 * 128];  // 32 KB
    int t = threadIdx.x;
    int row0 = blockIdx.x * 64;   // grid 1563; last block partially out of range

    // stage x1 = affine(yb) -> bf16, swizzled (1024 x 16B)
    for (int i = t; i < 1024; i += 512) {
        int r = i >> 4, kb = i & 15;
        int gr = row0 + r;
        ushort4 y0 = make_ushort4(0, 0, 0, 0), y1 = make_ushort4(0, 0, 0, 0);
        if (gr < NN) {
            long base = (long)gr * 32 + kb * 2;
            y0 = ((const ushort4*)yb)[base];
            y1 = ((const ushort4*)yb)[base + 1];
        }
        float4 a0 = ((const float4*)ac1)[kb * 2];
        float4 a1 = ((const float4*)ac1)[kb * 2 + 1];
        float4 c0 = ((const float4*)(ac1 + 128))[kb * 2];
        float4 c1 = ((const float4*)(ac1 + 128))[kb * 2 + 1];
        ushort4 o0, o1;
        o0.x = f2b(a0.x * b2f(y0.x) + c0.x);
        o0.y = f2b(a0.y * b2f(y0.y) + c0.y);
        o0.z = f2b(a0.z * b2f(y0.z) + c0.z);
        o0.w = f2b(a0.w * b2f(y0.w) + c0.w);
        o1.x = f2b(a1.x * b2f(y1.x) + c1.x);
        o1.y = f2b(a1.y * b2f(y1.y) + c1.y);
        o1.z = f2b(a1.z * b2f(y1.z) + c1.z);
        o1.w = f2b(a1.w * b2f(y1.w) + c1.w);
        ushort* dst = &xt[r * 128 + SWZ16(r, kb)];
        *(ushort4*)dst = o0;
        *(ushort4*)(dst + 4) = o1;
    }

    int wv = t >> 6, l = t & 63;
    int lr = l & 15, lg = l >> 4;
    int rw = wv & 3, jw = wv >> 2;
    int xrow = rw * 16 + lr;        // xrow & 15 == lr

    f32x4 z4 = {0.f, 0.f, 0.f, 0.f};
    f32x4 acc[4];
#pragma unroll
    for (int jt = 0; jt < 4; ++jt) acc[jt] = z4;

    for (int ch = 0; ch < 4; ++ch) {
        __syncthreads();   // wc free (prev GEMM2 done); xt staged (ch=0)
        // stage W1 chunk: linear async copy of pre-swizzled 32KB image
        {
            const ushort* src = W1img + ch * 16384;
#pragma unroll
            for (int i = 0; i < 4; ++i) {
                int u = (t + i * 512) * 8;
                gld_lds16(src + u, wc + u);
            }
        }
        __syncthreads();   // drains vmcnt -> wc = W1ch ready

        // GEMM1: hidden(16r x 64f per wave) = relu(x1 @ W1c + b1c)
        f32x4 hacc[4];
#pragma unroll
        for (int ft = 0; ft < 4; ++ft) hacc[ft] = z4;
#pragma unroll
        for (int ks = 0; ks < 4; ++ks) {
            int kcol = ((ks * 4 + lg) ^ lr) << 3;
            bf16x8 aR = *(const bf16x8*)&xt[xrow * 128 + kcol];
#pragma unroll
            for (int ft = 0; ft < 4; ++ft) {
                int f = jw * 64 + ft * 16 + lr;
                bf16x8 bW = *(const bf16x8*)&wc[f * 128 + kcol];
                hacc[ft] = __builtin_amdgcn_mfma_f32_16x16x32_bf16(aR, bW, hacc[ft], 0, 0, 0);
            }
        }
#pragma unroll
        for (int ft = 0; ft < 4; ++ft) {
            int fcol = jw * 64 + ft * 16 + lr;
            float b1v = b1[ch * 128 + fcol];
            int kbf = fcol >> 3, wi = fcol & 7;
#pragma unroll
            for (int rg = 0; rg < 4; ++rg) {
                int hrow = rw * 16 + lg * 4 + rg;
                ht[hrow * 128 + ((kbf ^ (hrow & 15)) << 3) + wi] =
                    f2b(fmaxf(hacc[ft][rg] + b1v, 0.f));
            }
        }
        __syncthreads();   // ht complete, wc free

        // stage W2 chunk: linear async copy of pre-swizzled 32KB image
        {
            const ushort* src = W2img + ch * 16384;
#pragma unroll
            for (int i = 0; i < 4; ++i) {
                int u = (t + i * 512) * 8;
                gld_lds16(src + u, wc + u);
            }
        }
        __syncthreads();   // drains vmcnt -> wc = W2ch ready

        // GEMM2 swapped: acc(j x r) += W2c-rows x ht-rows
#pragma unroll
        for (int ks = 0; ks < 4; ++ks) {
            int kcol = ((ks * 4 + lg) ^ lr) << 3;
            bf16x8 qR = *(const bf16x8*)&ht[xrow * 128 + kcol];
#pragma unroll
            for (int jt = 0; jt < 4; ++jt) {
                int j = jw * 64 + jt * 16 + lr;
                bf16x8 pW = *(const bf16x8*)&wc[j * 128 + kcol];
                acc[jt] = __builtin_amdgcn_mfma_f32_16x16x32_bf16(pW, qR, acc[jt], 0, 0, 0);
            }
        }
    }

    // epilogue: z = x1 + x2 + b2 -> zb (bf16), BN2 partials
    float sj[4][4], qj[4][4];
    int r = row0 + xrow;
#pragma unroll
    for (int jt = 0; jt < 4; ++jt) {
        int jb = jw * 64 + jt * 16 + lg * 4;
        float4 b2v = *(const float4*)&b2[jb];
        int kbj = jb >> 3, wj = jb & 7;
        ushort4 xv = *(const ushort4*)&xt[xrow * 128 + ((kbj ^ lr) << 3) + wj];
        float z0 = b2f(xv.x) + acc[jt][0] + b2v.x;
        float z1 = b2f(xv.y) + acc[jt][1] + b2v.y;
        float z2 = b2f(xv.z) + acc[jt][2] + b2v.z;
        float z3 = b2f(xv.w) + acc[jt][3] + b2v.w;
        if (r < NN) {
            ushort4 o;
            o.x = f2b(z0); o.y = f2b(z1); o.z = f2b(z2); o.w = f2b(z3);
            *(ushort4*)&zb[(long)r * 128 + jb] = o;
            sj[jt][0] = z0; sj[jt][1] = z1; sj[jt][2] = z2; sj[jt][3] = z3;
            qj[jt][0] = z0 * z0; qj[jt][1] = z1 * z1; qj[jt][2] = z2 * z2; qj[jt][3] = z3 * z3;
        } else {
            sj[jt][0] = 0.f; sj[jt][1] = 0.f; sj[jt][2] = 0.f; sj[jt][3] = 0.f;
            qj[jt][0] = 0.f; qj[jt][1] = 0.f; qj[jt][2] = 0.f; qj[jt][3] = 0.f;
        }
    }
#pragma unroll
    for (int jt = 0; jt < 4; ++jt)
#pragma unroll
        for (int g = 0; g < 4; ++g) {
#pragma unroll
            for (int d = 1; d < 16; d <<= 1) {
                sj[jt][g] += __shfl_xor(sj[jt][g], d);
                qj[jt][g] += __shfl_xor(qj[jt][g], d);
            }
        }
    __syncthreads();   // ht reads done; reuse as reduction buffer
    float* redS = (float*)&ht[0];    // [8][128]
    float* redQ = redS + 1024;       // [8][128]
    if (lr == 0) {
#pragma unroll
        for (int jt = 0; jt < 4; ++jt)
#pragma unroll
            for (int g = 0; g < 4; ++g) {
                int j = jw * 64 + jt * 16 + lg * 4 + g;
                redS[wv * 128 + j] = sj[jt][g];
                redQ[wv * 128 + j] = qj[jt][g];
            }
    }
    __syncthreads();
    if (t < 128) {
        int h = t >> 6;   // j-half; owned by waves h*4 .. h*4+3
        float S = redS[(h * 4 + 0) * 128 + t] + redS[(h * 4 + 1) * 128 + t]
                + redS[(h * 4 + 2) * 128 + t] + redS[(h * 4 + 3) * 128 + t];
        float Q = redQ[(h * 4 + 0) * 128 + t] + redQ[(h * 4 + 1) * 128 + t]
                + redQ[(h * 4 + 2) * 128 + t] + redQ[(h * 4 + 3) * 128 + t];
        atomicAdd(&stats2[t], S);
        atomicAdd(&stats2[128 + t], Q);
    }
}

// ---------------- launch ----------------

extern "C" void kernel_launch(void* const* d_in, const int* in_sizes, int n_in,
                              void* d_out, int out_size, void* d_ws, size_t ws_size,
                              hipStream_t stream) {
    const float* x     = (const float*)d_in[0];
    const int*   ei    = (const int*)d_in[1];
    const float* ew    = (const float*)d_in[2];
    const float* W     = (const float*)d_in[3];
    const float* b     = (const float*)d_in[4];
    const float* gamma = (const float*)d_in[5];
    const float* beta  = (const float*)d_in[6];
    const float* W1    = (const float*)d_in[7];
    const float* b1    = (const float*)d_in[8];
    const float* W2    = (const float*)d_in[9];
    const float* b2    = (const float*)d_in[10];
    float* out = (float*)d_out;
    float* ws  = (float*)d_ws;

    ull*   pk     = (ull*)ws;                        // NN (8B each)
    float* dinv   = ws + 2 * NN;                     // NN
    float* stats1 = ws + 3 * NN;                     // 256
    float* ac1    = stats1 + 256;                    // 256
    float* stats2 = ac1 + 256;                       // 256
    float* ac2    = stats2 + 256;                    // 256
    ushort* xb    = (ushort*)(ws + 3 * NN + 1024);   // NN*128 bf16
    ushort* WTb   = xb + (long)NN * 128;             // 16384
    ushort* W1img = WTb + 16384;                     // 65536
    ushort* W2img = W1img + 65536;                   // 65536
    float*  fend  = ws + 3 * NN + 1024 + (long)NN * 64 + 73728;
    int*   cnt    = (int*)fend;                      // NN
    int*   start  = cnt + NN;                        // NN+1
    int*   bsum   = start + NN + 1;                  // SCB
    int*   bbase  = bsum + SCB;                      // SCB
    uint2* csr    = (uint2*)(((uintptr_t)(bbase + SCB) + 7) & ~(uintptr_t)7);  // EE records
    ushort* aggx  = (ushort*)(csr + EE);             // NN*128 bf16
    int*   rank   = (int*)aggx;                      // EE ints; lifetime before aggx (disjoint)
    ushort* yb    = xb;                              // xb becomes y (bf16) in-place in k_conv
    ushort* zb    = aggx;                            // aggx dead after k_conv; reuse for bf16 z

    int nb = (NN + 63) / 64;   // 1563

    k_init<<<(NN + 255) / 256, 256, 0, stream>>>(pk, stats1, stats2);
    k_pre<<<MIXB + 576, 256, 0, stream>>>(ei, ew, pk, rank, x, xb, W, W1, W2, WTb, W1img, W2img);
    k_scan_part<<<SCB, 256, 0, stream>>>(pk, cnt, dinv, bsum);
    k_scan_base<<<1, 128, 0, stream>>>(bsum, bbase, start);
    k_scan_fin<<<SCB, 256, 0, stream>>>(cnt, bbase, start);
    k_fill<<<EE / 256, 256, 0, stream>>>(ei, ew, dinv, start, rank, csr);
    k_gather<<<NN / 32, 256, 0, stream>>>(xb, dinv, start, csr, aggx);
    k_conv<<<nb, 256, 0, stream>>>(aggx, WTb, b, yb, stats1);
    k_bn_fin<<<1, 128, 0, stream>>>(stats1, gamma, beta, ac1);
    k_mlp<<<nb, 512, 0, stream>>>(yb, ac1, W1img, b1, W2img, b2, zb, stats2);
    k_bn_fin<<<1, 128, 0, stream>>>(stats2, gamma, beta, ac2);
    k_affine2<<<(NN * 32) / 256, 256, 0, stream>>>(zb, ac2, out);
}

// Round 17
// 345.866 us; speedup vs baseline: 1.1101x; 1.0005x over previous
//
#include <hip/hip_runtime.h>

#define NN 100000
#define EE 1600000
#define DD 128
#define FFD 512
#define EPSV 1e-5f

#define SCB 98      // scan blocks: ceil(100000/1024)
#define EB 6250     // edge blocks in k_pre
#define MIXB 18750  // EB*3 (1 edge : 2 xb interleave)

typedef __attribute__((ext_vector_type(8))) short bf16x8;
typedef __attribute__((ext_vector_type(4))) float f32x4;
typedef unsigned long long ull;

__device__ __forceinline__ ushort f2b(float f) {          // fp32 -> bf16 RNE
    uint u = __float_as_uint(f);
    return (ushort)((u + 0x7FFF + ((u >> 16) & 1)) >> 16);
}
__device__ __forceinline__ float b2f(ushort u) {
    return __uint_as_float(((uint)u) << 16);
}

// async 16B global->LDS copy (linear dest; vmcnt-drained by __syncthreads)
__device__ __forceinline__ void gld_lds16(const ushort* g, ushort* l) {
    __builtin_amdgcn_global_load_lds(
        (const __attribute__((address_space(1))) uint*)g,
        (__attribute__((address_space(3))) uint*)l, 16, 0, 0);
}

// ---------------- init: pk=0, stats=0 ----------------

__global__ __launch_bounds__(256) void k_init(ull* pk, float* s1, float* s2) {
    int i = blockIdx.x * 256 + threadIdx.x;
    if (i < NN) pk[i] = 0ULL;
    if (blockIdx.x == 0) { s1[threadIdx.x] = 0.f; s2[threadIdx.x] = 0.f; }
}

// ---------------- fused pre-pass: edge_deg (atomics) || x->bf16 || weight images ----------------
// WTimg/W1img/W2img are swizzled LDS images so GEMM kernels stage with linear global_load_lds.

__global__ __launch_bounds__(256) void k_pre(const int* __restrict__ ei,
                                             const float* __restrict__ ew,
                                             ull* __restrict__ pk,
                                             int* __restrict__ rank,
                                             const float* __restrict__ x,
                                             ushort* __restrict__ xb,
                                             const float* __restrict__ W,
                                             const float* __restrict__ W1,
                                             const float* __restrict__ W2,
                                             ushort* __restrict__ WTimg,
                                             ushort* __restrict__ W1img,
                                             ushort* __restrict__ W2img) {
    int bid = blockIdx.x;
    int t = threadIdx.x;
    if (bid < MIXB) {
        if (bid % 3 == 0) {
            int e = (bid / 3) * 256 + t;   // EB*256 == EE exactly
            int dst = ei[EE + e];
            uint fx = (uint)(ew[e] * 16777216.0f + 0.5f);
            ull old = atomicAdd(&pk[dst], (1ULL << 32) | (ull)fx);
            rank[e] = (int)(old >> 32);
        } else {
            int xbk = bid - bid / 3 - 1;   // 0..12499
            long i = (long)xbk * 256 + t;
            float4 v = ((const float4*)x)[i];
            ushort4 o;
            o.x = f2b(v.x); o.y = f2b(v.y); o.z = f2b(v.z); o.w = f2b(v.w);
            ((ushort4*)xb)[i] = o;
        }
    } else {
        int i = (bid - MIXB) * 256 + t;
        if (i < 16384) {
            // WTimg[u]: swizzled image of W^T (row n = out feature, col = k slot)
            int n = i >> 7, col = i & 127;
            int k = ((((col >> 3) ^ (n & 15)) << 3)) + (col & 7);
            WTimg[i] = f2b(W[k * 128 + n]);
        } else if (i < 16384 + 65536) {
            // W1img[u]: per-chunk swizzled [f_local][k] image
            int u = i - 16384;
            int ch = u >> 14, rem = u & 16383;
            int f = rem >> 7, col = rem & 127;
            int kb = (col >> 3) ^ (f & 15);
            int j = col & 7;
            W1img[u] = f2b(W1[(kb * 8 + j) * 512 + ch * 128 + f]);
        } else {
            // W2img[u]: per-chunk swizzled [j_row][f_local] image
            int u = i - 16384 - 65536;
            int ch = u >> 14, rem = u & 16383;
            int jrow = rem >> 7, col = rem & 127;
            int kb = (col >> 3) ^ (jrow & 15);
            int j2 = col & 7;
            W2img[u] = f2b(W2[(ch * 128 + kb * 8 + j2) * 128 + jrow]);
        }
    }
}

// ---------------- scan part 1: block sums; unpack pk -> cnt, dinv ----------------

__global__ __launch_bounds__(256) void k_scan_part(const ull* __restrict__ pk,
                                                   int* __restrict__ cnt,
                                                   float* __restrict__ dinv,
                                                   int* __restrict__ bsum) {
    __shared__ int red[4];
    int b = blockIdx.x, t = threadIdx.x;
    int base = b * 1024 + t * 4;
    int s = 0;
#pragma unroll
    for (int j = 0; j < 4; ++j) {
        int i = base + j;
        if (i < NN) {
            ull v = pk[i];
            int c = (int)(v >> 32);
            cnt[i] = c;
            dinv[i] = rsqrtf(1.0f + (float)(uint)(v & 0xFFFFFFFFu) * (1.0f / 16777216.0f));
            s += c;
        }
    }
#pragma unroll
    for (int d = 1; d < 64; d <<= 1) s += __shfl_xor(s, d);
    if ((t & 63) == 0) red[t >> 6] = s;
    __syncthreads();
    if (t == 0) bsum[b] = red[0] + red[1] + red[2] + red[3];
}

__global__ __launch_bounds__(128) void k_scan_base(int* __restrict__ bsum,
                                                   int* __restrict__ bbase,
                                                   int* __restrict__ start) {
    if (threadIdx.x == 0) {
        int run = 0;
        for (int i = 0; i < SCB; ++i) { bbase[i] = run; run += bsum[i]; }
        start[NN] = run;   // == EE
    }
}

__global__ __launch_bounds__(256) void k_scan_fin(const int* __restrict__ cnt,
                                                  const int* __restrict__ bbase,
                                                  int* __restrict__ start) {
    __shared__ int ts[256];
    int b = blockIdx.x, t = threadIdx.x;
    int base = b * 1024 + t * 4;
    int v[4];
    int s = 0;
#pragma unroll
    for (int j = 0; j < 4; ++j) {
        int i = base + j;
        v[j] = (i < NN) ? cnt[i] : 0;
        s += v[j];
    }
    ts[t] = s;
    __syncthreads();
    for (int d = 1; d < 256; d <<= 1) {
        int add = (t >= d) ? ts[t - d] : 0;
        __syncthreads();
        ts[t] += add;
        __syncthreads();
    }
    int run = bbase[b] + ts[t] - s;   // exclusive offset for this thread
#pragma unroll
    for (int j = 0; j < 4; ++j) {
        int i = base + j;
        if (i < NN) {
            start[i] = run;
            run += v[j];
        }
    }
}

// ---------------- fill CSR records (src, norm), ATOMIC-FREE via rank ----------------

__global__ __launch_bounds__(256) void k_fill(const int* __restrict__ ei,
                                              const float* __restrict__ ew,
                                              const float* __restrict__ dinv,
                                              const int* __restrict__ start,
                                              const int* __restrict__ rank,
                                              uint2* __restrict__ csr) {
    int e = blockIdx.x * 256 + threadIdx.x;
    if (e < EE) {
        int src = ei[e];
        int dst = ei[EE + e];
        float nrm = dinv[src] * ew[e] * dinv[dst];
        int pos = start[dst] + rank[e];
        csr[pos] = make_uint2((uint)src, __float_as_uint(nrm));
    }
}

// ---------------- fused gather + conv GEMM ----------------
// 64 nodes/block, 8 waves. Phase 1: agg = dinv^2*x~ + sum norm*x~[src] -> swizzled LDS.
// Phase 2: y = x~ + agg @ W + b -> ybuf (bf16), BN1 stats. W async-staged from WTimg.
// Swapped MFMA: lane holds 4 consecutive out-features per reg, row = xrow.

#define SWZ16(row, kb) ((((kb) ^ ((row) & 15)) << 3))

__global__ __launch_bounds__(512, 6) void k_gconv(const ushort* __restrict__ xb,
                                                  const float* __restrict__ dinv,
                                                  const int* __restrict__ start,
                                                  const uint2* __restrict__ csr,
                                                  const ushort* __restrict__ WTimg,
                                                  const float* __restrict__ b,
                                                  ushort* __restrict__ ybuf,
                                                  float* __restrict__ stats1) {
    __shared__ __align__(16) ushort xt[64 * 128];   // 16 KB agg tile (swizzled)
    __shared__ __align__(16) ushort wc[128 * 128];  // 32 KB W image
    int t = threadIdx.x;
    int row0 = blockIdx.x * 64;   // grid 1563; last block partial
    int wv = t >> 6, l = t & 63;

    // async stage W image (linear 32KB)
#pragma unroll
    for (int i = 0; i < 4; ++i) {
        int u = (t + i * 512) * 8;
        gld_lds16(WTimg + u, wc + u);
    }

    // gather 8 nodes per wave -> xt (lane handles 2 features)
    const uint* xbu = (const uint*)xb;
    for (int k = 0; k < 8; ++k) {
        int rloc = wv * 8 + k;
        int node = row0 + rloc;
        float a0 = 0.f, a1 = 0.f;
        if (node < NN) {
            int e0 = start[node], e1 = start[node + 1];
            int i = e0;
            for (; i + 8 <= e1; i += 8) {
                uint2 rr[8];
                uint hh[8];
#pragma unroll
                for (int u = 0; u < 8; ++u) rr[u] = csr[i + u];
#pragma unroll
                for (int u = 0; u < 8; ++u) hh[u] = xbu[rr[u].x * 64 + l];
#pragma unroll
                for (int u = 0; u < 8; ++u) {
                    float n = __uint_as_float(rr[u].y);
                    a0 = fmaf(n, b2f((ushort)(hh[u] & 0xFFFF)), a0);
                    a1 = fmaf(n, b2f((ushort)(hh[u] >> 16)), a1);
                }
            }
            if (i + 4 <= e1) {
                uint2 rr[4];
                uint hh[4];
#pragma unroll
                for (int u = 0; u < 4; ++u) rr[u] = csr[i + u];
#pragma unroll
                for (int u = 0; u < 4; ++u) hh[u] = xbu[rr[u].x * 64 + l];
#pragma unroll
                for (int u = 0; u < 4; ++u) {
                    float n = __uint_as_float(rr[u].y);
                    a0 = fmaf(n, b2f((ushort)(hh[u] & 0xFFFF)), a0);
                    a1 = fmaf(n, b2f((ushort)(hh[u] >> 16)), a1);
                }
                i += 4;
            }
            for (; i < e1; ++i) {
                uint2 r0 = csr[i];
                uint h0 = xbu[r0.x * 64 + l];
                float n0 = __uint_as_float(r0.y);
                a0 = fmaf(n0, b2f((ushort)(h0 & 0xFFFF)), a0);
                a1 = fmaf(n0, b2f((ushort)(h0 >> 16)), a1);
            }
            float dv = dinv[node];
            float sl = dv * dv;
            uint hs = xbu[(long)node * 64 + l];
            a0 = fmaf(sl, b2f((ushort)(hs & 0xFFFF)), a0);
            a1 = fmaf(sl, b2f((ushort)(hs >> 16)), a1);
        }
        int col = 2 * l;
        uint pv = (uint)f2b(a0) | ((uint)f2b(a1) << 16);
        *(uint*)&xt[rloc * 128 + SWZ16(rloc, col >> 3) + (col & 7)] = pv;
    }
    __syncthreads();   // xt complete; gld_lds drained -> wc ready

    int lr = l & 15, lg = l >> 4;
    int rw = wv & 3, jw = wv >> 2;
    int xrow = rw * 16 + lr;

    f32x4 z4 = {0.f, 0.f, 0.f, 0.f};
    f32x4 acc[4];
#pragma unroll
    for (int jt = 0; jt < 4; ++jt) acc[jt] = z4;

#pragma unroll
    for (int ks = 0; ks < 4; ++ks) {
        int kcol = ((ks * 4 + lg) ^ lr) << 3;
        bf16x8 qR = *(const bf16x8*)&xt[xrow * 128 + kcol];
#pragma unroll
        for (int jt = 0; jt < 4; ++jt) {
            int f = jw * 64 + jt * 16 + lr;
            bf16x8 pW = *(const bf16x8*)&wc[f * 128 + kcol];
            acc[jt] = __builtin_amdgcn_mfma_f32_16x16x32_bf16(pW, qR, acc[jt], 0, 0, 0);
        }
    }

    // epilogue: y = x~ + acc + b -> ybuf (bf16), BN1 partials
    float sj[4][4], qj[4][4];
    int r = row0 + xrow;
#pragma unroll
    for (int jt = 0; jt < 4; ++jt) {
        int jb = jw * 64 + jt * 16 + lg * 4;
        float4 bv = *(const float4*)&b[jb];
        if (r < NN) {
            ushort4 xv = *(const ushort4*)&xb[(long)r * 128 + jb];
            float z0 = b2f(xv.x) + acc[jt][0] + bv.x;
            float z1 = b2f(xv.y) + acc[jt][1] + bv.y;
            float z2 = b2f(xv.z) + acc[jt][2] + bv.z;
            float z3 = b2f(xv.w) + acc[jt][3] + bv.w;
            ushort4 o;
            o.x = f2b(z0); o.y = f2b(z1); o.z = f2b(z2); o.w = f2b(z3);
            *(ushort4*)&ybuf[(long)r * 128 + jb] = o;
            sj[jt][0] = z0; sj[jt][1] = z1; sj[jt][2] = z2; sj[jt][3] = z3;
            qj[jt][0] = z0 * z0; qj[jt][1] = z1 * z1; qj[jt][2] = z2 * z2; qj[jt][3] = z3 * z3;
        } else {
            sj[jt][0] = 0.f; sj[jt][1] = 0.f; sj[jt][2] = 0.f; sj[jt][3] = 0.f;
            qj[jt][0] = 0.f; qj[jt][1] = 0.f; qj[jt][2] = 0.f; qj[jt][3] = 0.f;
        }
    }
#pragma unroll
    for (int jt = 0; jt < 4; ++jt)
#pragma unroll
        for (int g = 0; g < 4; ++g) {
#pragma unroll
            for (int d = 1; d < 16; d <<= 1) {
                sj[jt][g] += __shfl_xor(sj[jt][g], d);
                qj[jt][g] += __shfl_xor(qj[jt][g], d);
            }
        }
    __syncthreads();   // xt reads done; reuse as reduction buffer
    float* redS = (float*)&xt[0];    // [8][128]
    float* redQ = redS + 1024;       // [8][128]
    if (lr == 0) {
#pragma unroll
        for (int jt = 0; jt < 4; ++jt)
#pragma unroll
            for (int g = 0; g < 4; ++g) {
                int j = jw * 64 + jt * 16 + lg * 4 + g;
                redS[wv * 128 + j] = sj[jt][g];
                redQ[wv * 128 + j] = qj[jt][g];
            }
    }
    __syncthreads();
    if (t < 128) {
        int h = t >> 6;   // j-half; owned by waves h*4 .. h*4+3
        float S = redS[(h * 4 + 0) * 128 + t] + redS[(h * 4 + 1) * 128 + t]
                + redS[(h * 4 + 2) * 128 + t] + redS[(h * 4 + 3) * 128 + t];
        float Q = redQ[(h * 4 + 0) * 128 + t] + redQ[(h * 4 + 1) * 128 + t]
                + redQ[(h * 4 + 2) * 128 + t] + redQ[(h * 4 + 3) * 128 + t];
        atomicAdd(&stats1[t], S);
        atomicAdd(&stats1[128 + t], Q);
    }
}

// ---------------- BN finalize ----------------

__global__ __launch_bounds__(128) void k_bn_fin(const float* __restrict__ stats,
                                                const float* __restrict__ gamma,
                                                const float* __restrict__ beta,
                                                float* __restrict__ ac) {
    int c = threadIdx.x;
    float mu = stats[c] * (1.0f / NN);
    float var = stats[128 + c] * (1.0f / NN) - mu * mu;
    float a = gamma[c] * rsqrtf(var + EPSV);
    ac[c] = a;
    ac[128 + c] = beta[c] - mu * a;
}

// ---------------- final affine: out = a * zb + c (bf16 in, fp32 out) ----------------

__global__ __launch_bounds__(256) void k_affine2(const ushort* __restrict__ zb,
                                                 const float* __restrict__ ac,
                                                 float* __restrict__ out) {
    long i = (long)blockIdx.x * 256 + threadIdx.x;   // float4 units
    int c4i = (int)(i & 31);
    float4 a = ((const float4*)ac)[c4i];
    float4 cc = ((const float4*)(ac + 128))[c4i];
    ushort4 zv = ((const ushort4*)zb)[i];
    float4 o;
    o.x = a.x * b2f(zv.x) + cc.x;
    o.y = a.y * b2f(zv.y) + cc.y;
    o.z = a.z * b2f(zv.z) + cc.z;
    o.w = a.w * b2f(zv.w) + cc.w;
    ((float4*)out)[i] = o;
}

// ---------------- fused MLP v10: async image staging + swapped GEMM1 (b64 ht writes) ----------------

__global__ __launch_bounds__(512, 4) void k_mlp(const ushort* __restrict__ yb,
                                                const float* __restrict__ ac1,
                                                const ushort* __restrict__ W1img,
                                                const float* __restrict__ b1,
                                                const ushort* __restrict__ W2img,
                                                const float* __restrict__ b2,
                                                ushort* __restrict__ zb,
                                                float* __restrict__ stats2) {
    __shared__ __align__(16) ushort xt[64 * 128];   // 16 KB
    __shared__ __align__(16) ushort ht[64 * 128];   // 16 KB
    __shared__ __align__(16) ushort wc[128 * 128];  // 32 KB
    int t = threadIdx.x;
    int row0 = blockIdx.x * 64;   // grid 1563; last block partial

    // stage x1 = affine(yb) -> bf16, swizzled (1024 x 16B)
    for (int i = t; i < 1024; i += 512) {
        int r = i >> 4, kb = i & 15;
        int gr = row0 + r;
        ushort4 y0 = make_ushort4(0, 0, 0, 0), y1 = make_ushort4(0, 0, 0, 0);
        if (gr < NN) {
            long base = (long)gr * 32 + kb * 2;
            y0 = ((const ushort4*)yb)[base];
            y1 = ((const ushort4*)yb)[base + 1];
        }
        float4 a0 = ((const float4*)ac1)[kb * 2];
        float4 a1 = ((const float4*)ac1)[kb * 2 + 1];
        float4 c0 = ((const float4*)(ac1 + 128))[kb * 2];
        float4 c1 = ((const float4*)(ac1 + 128))[kb * 2 + 1];
        ushort4 o0, o1;
        o0.x = f2b(a0.x * b2f(y0.x) + c0.x);
        o0.y = f2b(a0.y * b2f(y0.y) + c0.y);
        o0.z = f2b(a0.z * b2f(y0.z) + c0.z);
        o0.w = f2b(a0.w * b2f(y0.w) + c0.w);
        o1.x = f2b(a1.x * b2f(y1.x) + c1.x);
        o1.y = f2b(a1.y * b2f(y1.y) + c1.y);
        o1.z = f2b(a1.z * b2f(y1.z) + c1.z);
        o1.w = f2b(a1.w * b2f(y1.w) + c1.w);
        ushort* dst = &xt[r * 128 + SWZ16(r, kb)];
        *(ushort4*)dst = o0;
        *(ushort4*)(dst + 4) = o1;
    }

    int wv = t >> 6, l = t & 63;
    int lr = l & 15, lg = l >> 4;
    int rw = wv & 3, jw = wv >> 2;
    int xrow = rw * 16 + lr;        // xrow & 15 == lr

    f32x4 z4 = {0.f, 0.f, 0.f, 0.f};
    f32x4 acc[4];
#pragma unroll
    for (int jt = 0; jt < 4; ++jt) acc[jt] = z4;

    for (int ch = 0; ch < 4; ++ch) {
        __syncthreads();   // wc free (prev GEMM2 done); xt staged (ch=0)
        // stage W1 chunk: linear async copy of pre-swizzled 32KB image
        {
            const ushort* src = W1img + ch * 16384;
#pragma unroll
            for (int i = 0; i < 4; ++i) {
                int u = (t + i * 512) * 8;
                gld_lds16(src + u, wc + u);
            }
        }
        __syncthreads();   // drains vmcnt -> wc = W1ch ready

        // GEMM1 SWAPPED: hacc[ft] holds 4 consecutive f per reg, col = xrow
        f32x4 hacc[4];
#pragma unroll
        for (int ft = 0; ft < 4; ++ft) hacc[ft] = z4;
#pragma unroll
        for (int ks = 0; ks < 4; ++ks) {
            int kcol = ((ks * 4 + lg) ^ lr) << 3;
            bf16x8 aR = *(const bf16x8*)&xt[xrow * 128 + kcol];
#pragma unroll
            for (int ft = 0; ft < 4; ++ft) {
                int f = jw * 64 + ft * 16 + lr;
                bf16x8 bW = *(const bf16x8*)&wc[f * 128 + kcol];
                hacc[ft] = __builtin_amdgcn_mfma_f32_16x16x32_bf16(bW, aR, hacc[ft], 0, 0, 0);
            }
        }
#pragma unroll
        for (int ft = 0; ft < 4; ++ft) {
            int fc = jw * 64 + ft * 16 + lg * 4;
            float4 b1v = *(const float4*)&b1[ch * 128 + fc];
            ushort4 o;
            o.x = f2b(fmaxf(hacc[ft][0] + b1v.x, 0.f));
            o.y = f2b(fmaxf(hacc[ft][1] + b1v.y, 0.f));
            o.z = f2b(fmaxf(hacc[ft][2] + b1v.z, 0.f));
            o.w = f2b(fmaxf(hacc[ft][3] + b1v.w, 0.f));
            *(ushort4*)&ht[xrow * 128 + (((fc >> 3) ^ lr) << 3) + (fc & 7)] = o;
        }
        __syncthreads();   // ht complete, wc free

        // stage W2 chunk: linear async copy of pre-swizzled 32KB image
        {
            const ushort* src = W2img + ch * 16384;
#pragma unroll
            for (int i = 0; i < 4; ++i) {
                int u = (t + i * 512) * 8;
                gld_lds16(src + u, wc + u);
            }
        }
        __syncthreads();   // drains vmcnt -> wc = W2ch ready

        // GEMM2 swapped: acc(j x r) += W2c-rows x ht-rows
#pragma unroll
        for (int ks = 0; ks < 4; ++ks) {
            int kcol = ((ks * 4 + lg) ^ lr) << 3;
            bf16x8 qR = *(const bf16x8*)&ht[xrow * 128 + kcol];
#pragma unroll
            for (int jt = 0; jt < 4; ++jt) {
                int j = jw * 64 + jt * 16 + lr;
                bf16x8 pW = *(const bf16x8*)&wc[j * 128 + kcol];
                acc[jt] = __builtin_amdgcn_mfma_f32_16x16x32_bf16(pW, qR, acc[jt], 0, 0, 0);
            }
        }
    }

    // epilogue: z = x1 + x2 + b2 -> zb (bf16), BN2 partials
    float sj[4][4], qj[4][4];
    int r = row0 + xrow;
#pragma unroll
    for (int jt = 0; jt < 4; ++jt) {
        int jb = jw * 64 + jt * 16 + lg * 4;
        float4 b2v = *(const float4*)&b2[jb];
        int kbj = jb >> 3, wj = jb & 7;
        ushort4 xv = *(const ushort4*)&xt[xrow * 128 + ((kbj ^ lr) << 3) + wj];
        float z0 = b2f(xv.x) + acc[jt][0] + b2v.x;
        float z1 = b2f(xv.y) + acc[jt][1] + b2v.y;
        float z2 = b2f(xv.z) + acc[jt][2] + b2v.z;
        float z3 = b2f(xv.w) + acc[jt][3] + b2v.w;
        if (r < NN) {
            ushort4 o;
            o.x = f2b(z0); o.y = f2b(z1); o.z = f2b(z2); o.w = f2b(z3);
            *(ushort4*)&zb[(long)r * 128 + jb] = o;
            sj[jt][0] = z0; sj[jt][1] = z1; sj[jt][2] = z2; sj[jt][3] = z3;
            qj[jt][0] = z0 * z0; qj[jt][1] = z1 * z1; qj[jt][2] = z2 * z2; qj[jt][3] = z3 * z3;
        } else {
            sj[jt][0] = 0.f; sj[jt][1] = 0.f; sj[jt][2] = 0.f; sj[jt][3] = 0.f;
            qj[jt][0] = 0.f; qj[jt][1] = 0.f; qj[jt][2] = 0.f; qj[jt][3] = 0.f;
        }
    }
#pragma unroll
    for (int jt = 0; jt < 4; ++jt)
#pragma unroll
        for (int g = 0; g < 4; ++g) {
#pragma unroll
            for (int d = 1; d < 16; d <<= 1) {
                sj[jt][g] += __shfl_xor(sj[jt][g], d);
                qj[jt][g] += __shfl_xor(qj[jt][g], d);
            }
        }
    __syncthreads();   // ht reads done; reuse as reduction buffer
    float* redS = (float*)&ht[0];    // [8][128]
    float* redQ = redS + 1024;       // [8][128]
    if (lr == 0) {
#pragma unroll
        for (int jt = 0; jt < 4; ++jt)
#pragma unroll
            for (int g = 0; g < 4; ++g) {
                int j = jw * 64 + jt * 16 + lg * 4 + g;
                redS[wv * 128 + j] = sj[jt][g];
                redQ[wv * 128 + j] = qj[jt][g];
            }
    }
    __syncthreads();
    if (t < 128) {
        int h = t >> 6;   // j-half; owned by waves h*4 .. h*4+3
        float S = redS[(h * 4 + 0) * 128 + t] + redS[(h * 4 + 1) * 128 + t]
                + redS[(h * 4 + 2) * 128 + t] + redS[(h * 4 + 3) * 128 + t];
        float Q = redQ[(h * 4 + 0) * 128 + t] + redQ[(h * 4 + 1) * 128 + t]
                + redQ[(h * 4 + 2) * 128 + t] + redQ[(h * 4 + 3) * 128 + t];
        atomicAdd(&stats2[t], S);
        atomicAdd(&stats2[128 + t], Q);
    }
}

// ---------------- launch ----------------

extern "C" void kernel_launch(void* const* d_in, const int* in_sizes, int n_in,
                              void* d_out, int out_size, void* d_ws, size_t ws_size,
                              hipStream_t stream) {
    const float* x     = (const float*)d_in[0];
    const int*   ei    = (const int*)d_in[1];
    const float* ew    = (const float*)d_in[2];
    const float* W     = (const float*)d_in[3];
    const float* b     = (const float*)d_in[4];
    const float* gamma = (const float*)d_in[5];
    const float* beta  = (const float*)d_in[6];
    const float* W1    = (const float*)d_in[7];
    const float* b1    = (const float*)d_in[8];
    const float* W2    = (const float*)d_in[9];
    const float* b2    = (const float*)d_in[10];
    float* out = (float*)d_out;
    float* ws  = (float*)d_ws;

    ull*   pk     = (ull*)ws;                        // NN (8B each)
    float* dinv   = ws + 2 * NN;                     // NN
    float* stats1 = ws + 3 * NN;                     // 256
    float* ac1    = stats1 + 256;                    // 256
    float* stats2 = ac1 + 256;                       // 256
    float* ac2    = stats2 + 256;                    // 256
    ushort* xb    = (ushort*)(ws + 3 * NN + 1024);   // NN*128 bf16
    ushort* WTimg = xb + (long)NN * 128;             // 16384
    ushort* W1img = WTimg + 16384;                   // 65536
    ushort* W2img = W1img + 65536;                   // 65536
    float*  fend  = ws + 3 * NN + 1024 + (long)NN * 64 + 73728;
    int*   cnt    = (int*)fend;                      // NN
    int*   start  = cnt + NN;                        // NN+1
    int*   bsum   = start + NN + 1;                  // SCB
    int*   bbase  = bsum + SCB;                      // SCB
    uint2* csr    = (uint2*)(((uintptr_t)(bbase + SCB) + 7) & ~(uintptr_t)7);  // EE records
    ushort* ybuf  = (ushort*)(csr + EE);             // NN*128 bf16 (y)
    int*   rank   = (int*)ybuf;                      // EE ints; lifetime before ybuf (disjoint)
    ushort* zb    = xb;                              // xb dead after k_gconv; reuse for bf16 z

    int nb = (NN + 63) / 64;   // 1563

    k_init<<<(NN + 255) / 256, 256, 0, stream>>>(pk, stats1, stats2);
    k_pre<<<MIXB + 576, 256, 0, stream>>>(ei, ew, pk, rank, x, xb, W, W1, W2, WTimg, W1img, W2img);
    k_scan_part<<<SCB, 256, 0, stream>>>(pk, cnt, dinv, bsum);
    k_scan_base<<<1, 128, 0, stream>>>(bsum, bbase, start);
    k_scan_fin<<<SCB, 256, 0, stream>>>(cnt, bbase, start);
    k_fill<<<EE / 256, 256, 0, stream>>>(ei, ew, dinv, start, rank, csr);
    k_gconv<<<nb, 512, 0, stream>>>(xb, dinv, start, csr, WTimg, b, ybuf, stats1);
    k_bn_fin<<<1, 128, 0, stream>>>(stats1, gamma, beta, ac1);
    k_mlp<<<nb, 512, 0, stream>>>(ybuf, ac1, W1img, b1, W2img, b2, zb, stats2);
    k_bn_fin<<<1, 128, 0, stream>>>(stats2, gamma, beta, ac2);
    k_affine2<<<(NN * 32) / 256, 256, 0, stream>>>(zb, ac2, out);
}